// Round 1
// baseline (477.019 us; speedup 1.0000x reference)
//
#include <hip/hip_runtime.h>
#include <cstdint>

typedef __bf16 bf16;
typedef __attribute__((ext_vector_type(8))) __bf16 bf16x8;
typedef __attribute__((ext_vector_type(4))) float f32x4;

#define CEPS 1e-5f
#define MROWS 65536   // B*T
#define NB 2048       // B
#define CDIM 512
#define K3C 1536

__device__ __forceinline__ float gelu_f(float x) {
  return 0.5f * x * (1.0f + erff(x * 0.70710678118654752440f));
}

__device__ __forceinline__ void gload_lds16(const void* g, void* l) {
  using GP = const __attribute__((address_space(1))) void*;
  using LP = __attribute__((address_space(3))) void*;
  __builtin_amdgcn_global_load_lds(reinterpret_cast<GP>(reinterpret_cast<uintptr_t>(g)),
                                   reinterpret_cast<LP>(reinterpret_cast<uintptr_t>(l)),
                                   16, 0, 0);
}

// ---------------- fold kernel: wmixf = wmix * bnm_scale (bf16); w1f = w1 * ln_g (bf16);
// b1f[n] = b1[n] + sum_c ln_b[c]*w1[n,c]
__global__ __launch_bounds__(256) void fold_kernel(
    const float* __restrict__ wmix, const float* __restrict__ bnm_g, const float* __restrict__ bnm_v,
    const float* __restrict__ edg, const float* __restrict__ edb,
    const float* __restrict__ esg, const float* __restrict__ esb,
    const float* __restrict__ w1a, const float* __restrict__ w1b,
    const float* __restrict__ b1a, const float* __restrict__ b1b,
    bf16* __restrict__ wmixf, bf16* __restrict__ w1f, float* __restrict__ b1f) {
  __shared__ float red[4];
  int bid = blockIdx.x, tid = threadIdx.x;
  if (bid < 512) {
    int o = bid;
    float s = bnm_g[o] * rsqrtf(bnm_v[o] + CEPS);
    for (int c = tid; c < K3C; c += 256)
      wmixf[(size_t)o * K3C + c] = (bf16)(wmix[(size_t)o * K3C + c] * s);
  } else {
    int n = bid - 512;
    int half = (n < 256) ? 0 : 1;
    const float* g  = half ? esg : edg;
    const float* lb = half ? esb : edb;
    const float* w1 = half ? w1b : w1a;
    const float* b1 = half ? b1b : b1a;
    int nn = n & 255;
    float dot = 0.f;
    for (int c = tid; c < 512; c += 256) {
      float w = w1[(size_t)nn * 512 + c];
      w1f[(size_t)n * 512 + c] = (bf16)(w * g[c]);
      dot += w * lb[c];
    }
    #pragma unroll
    for (int off = 1; off < 64; off <<= 1) dot += __shfl_xor(dot, off, 64);
    if ((tid & 63) == 0) red[tid >> 6] = dot;
    __syncthreads();
    if (tid == 0) b1f[n] = b1[nn] + red[0] + red[1] + red[2] + red[3];
  }
}

// ---------------- prep: x[b,c,64] -> tf, c3, c5 -> Acat[(b*32+t), {c, 512+c, 1024+c}] bf16
__global__ __launch_bounds__(512) void prep_kernel(
    const float* __restrict__ x,
    const float* __restrict__ w3, const float* __restrict__ bn3g, const float* __restrict__ bn3b,
    const float* __restrict__ bn3m, const float* __restrict__ bn3v,
    const float* __restrict__ w5, const float* __restrict__ bn5g, const float* __restrict__ bn5b,
    const float* __restrict__ bn5m, const float* __restrict__ bn5v,
    bf16* __restrict__ Acat) {
  int b = blockIdx.x, c = threadIdx.x;
  const float4* xp = (const float4*)(x + ((size_t)b * 512 + c) * 64);
  float tf[32];
  #pragma unroll
  for (int i = 0; i < 16; i++) {
    float4 v = xp[i];
    tf[2 * i]     = 0.5f * (v.x + v.y);
    tf[2 * i + 1] = 0.5f * (v.z + v.w);
  }
  float s3 = bn3g[c] * rsqrtf(bn3v[c] + CEPS), t3 = bn3b[c] - bn3m[c] * s3;
  float s5 = bn5g[c] * rsqrtf(bn5v[c] + CEPS), t5 = bn5b[c] - bn5m[c] * s5;
  float w30 = w3[c * 3], w31 = w3[c * 3 + 1], w32 = w3[c * 3 + 2];
  float w50 = w5[c * 5], w51 = w5[c * 5 + 1], w52 = w5[c * 5 + 2], w53 = w5[c * 5 + 3], w54 = w5[c * 5 + 4];
  bf16* Ab = Acat + (size_t)b * 32 * K3C + c;
  #pragma unroll
  for (int t = 0; t < 32; t++) {
    float tm2 = (t >= 2) ? tf[t - 2] : 0.f;
    float tm1 = (t >= 1) ? tf[t - 1] : 0.f;
    float tp1 = (t < 31) ? tf[t + 1] : 0.f;
    float tp2 = (t < 30) ? tf[t + 2] : 0.f;
    float c3 = gelu_f((w30 * tm1 + w31 * tf[t] + w32 * tp1) * s3 + t3);
    float c5 = gelu_f((w50 * tm2 + w51 * tm1 + w52 * tf[t] + w53 * tp1 + w54 * tp2) * s5 + t5);
    Ab[t * K3C]        = (bf16)tf[t];
    Ab[t * K3C + 512]  = (bf16)c3;
    Ab[t * K3C + 1024] = (bf16)c5;
  }
}

// ---------------- GEMM: out[m,n] = epi( sum_k A[m,k]*B[n,k] ), A row-major MxK bf16, B row-major NxK bf16
// EPI 0: gelu(acc + bnm_shift[n])              (mix path -> ctx)
// EPI 1: gelu(acc + b1f[n]) * (w2[n]/clip(temp)) (attn path -> gw)
#define BM 128
#define BN 128
#define BK 64

__device__ __forceinline__ int xcd_swz(int bid, int nwg) {
  int q = nwg >> 3, r = nwg & 7;
  int xcd = bid & 7, i = bid >> 3;
  return (xcd < r ? xcd * (q + 1) : r * (q + 1) + (xcd - r) * q) + i;
}

template <int EPI>
__global__ __launch_bounds__(256, 2) void gemm_bt(
    const bf16* __restrict__ A, const bf16* __restrict__ Bm, bf16* __restrict__ out,
    int M, int N, int K,
    const float* __restrict__ bn_g, const float* __restrict__ bn_b,
    const float* __restrict__ bn_m, const float* __restrict__ bn_v,
    const float* __restrict__ b1f,
    const float* __restrict__ w2a, const float* __restrict__ w2b,
    const float* __restrict__ ta, const float* __restrict__ tb) {
  __shared__ bf16 ldsA[2][BM * BK];
  __shared__ bf16 ldsB[2][BN * BK];
  int tid = threadIdx.x;
  int nblk = N / BN;
  int nwg = gridDim.x;
  int wgid = xcd_swz(blockIdx.x, nwg);
  int mb = wgid / nblk, nb = wgid % nblk;

  const bf16* Ag = A + (size_t)(mb * BM) * K;
  const bf16* Bg = Bm + (size_t)(nb * BN) * K;

  int lane = tid & 63;
  int wv = tid >> 6;
  int wm = wv >> 1, wn = wv & 1;
  int fr = lane & 15;
  int kq = lane >> 4;

  const f32x4 fzero = {0.f, 0.f, 0.f, 0.f};
  f32x4 acc[4][4];
  #pragma unroll
  for (int i = 0; i < 4; i++)
    #pragma unroll
    for (int j = 0; j < 4; j++) acc[i][j] = fzero;

  auto stage = [&](int buf, int k0) {
    #pragma unroll
    for (int i = 0; i < 4; i++) {
      int cch = i * 256 + tid;
      int row = cch >> 3;
      int cb = (cch & 7) << 4;
      const char* gpA = (const char*)Ag + (size_t)row * (K * 2) + k0 * 2 + cb;
      const char* gpB = (const char*)Bg + (size_t)row * (K * 2) + k0 * 2 + cb;
      int lbase = (i * 256 + (tid & ~63)) * 16;
      gload_lds16(gpA, (char*)&ldsA[buf][0] + lbase);
      gload_lds16(gpB, (char*)&ldsB[buf][0] + lbase);
    }
  };

  int kt = K / BK;
  stage(0, 0);
  __syncthreads();
  for (int t = 0; t < kt; t++) {
    int cur = t & 1;
    if (t + 1 < kt) stage(cur ^ 1, (t + 1) * BK);
    const bf16* la = &ldsA[cur][0];
    const bf16* lb = &ldsB[cur][0];
    #pragma unroll
    for (int kk = 0; kk < BK; kk += 32) {
      bf16x8 af[4], bfv[4];
      #pragma unroll
      for (int f = 0; f < 4; f++) {
        af[f]  = *(const bf16x8*)(la + (wm * 64 + f * 16 + fr) * BK + kk + kq * 8);
        bfv[f] = *(const bf16x8*)(lb + (wn * 64 + f * 16 + fr) * BK + kk + kq * 8);
      }
      #pragma unroll
      for (int fm = 0; fm < 4; fm++)
        #pragma unroll
        for (int fn = 0; fn < 4; fn++)
          acc[fm][fn] = __builtin_amdgcn_mfma_f32_16x16x32_bf16(af[fm], bfv[fn], acc[fm][fn], 0, 0, 0);
    }
    __syncthreads();
  }

  // epilogue
  #pragma unroll
  for (int fn = 0; fn < 4; fn++) {
    int n = nb * BN + wn * 64 + fn * 16 + fr;
    float bias, w2s;
    if (EPI == 0) {
      float s = bn_g[n] * rsqrtf(bn_v[n] + CEPS);
      bias = bn_b[n] - bn_m[n] * s;
      w2s = 1.f;
    } else {
      bias = b1f[n];
      float tv = (n < 256) ? ta[0] : tb[0];
      tv = fminf(fmaxf(tv, 0.25f), 4.0f);
      w2s = ((n < 256) ? w2a[n] : w2b[n - 256]) / tv;
    }
    #pragma unroll
    for (int fm = 0; fm < 4; fm++) {
      #pragma unroll
      for (int j = 0; j < 4; j++) {
        size_t m = (size_t)mb * BM + wm * 64 + fm * 16 + kq * 4 + j;
        float v = gelu_f(acc[fm][fn][j] + bias) * w2s;
        out[m * N + n] = (bf16)v;
      }
    }
  }
}

// ---------------- LN: z = tf + ctx + pos; feats = LN(z)*g+b (f32 -> d_out); zhat = standardize(feats) bf16
__global__ __launch_bounds__(256) void ln_kernel(
    const bf16* __restrict__ Acat, const bf16* __restrict__ ctx, const float* __restrict__ pos,
    const float* __restrict__ lng, const float* __restrict__ lnb,
    float* __restrict__ feats, bf16* __restrict__ zhat) {
  int m = blockIdx.x * 4 + (threadIdx.x >> 6);
  int lane = threadIdx.x & 63;
  int c0 = lane * 8;
  int t = m & 31;
  bf16x8 tf8 = *(const bf16x8*)(Acat + (size_t)m * K3C + c0);
  bf16x8 cx8 = *(const bf16x8*)(ctx + (size_t)m * 512 + c0);
  const float* pp = pos + t * 512 + c0;
  float z[8], s = 0.f, ss = 0.f;
  #pragma unroll
  for (int j = 0; j < 8; j++) {
    z[j] = (float)tf8[j] + (float)cx8[j] + pp[j];
    s += z[j]; ss += z[j] * z[j];
  }
  #pragma unroll
  for (int off = 1; off < 64; off <<= 1) { s += __shfl_xor(s, off, 64); ss += __shfl_xor(ss, off, 64); }
  float mu = s * (1.f / 512.f);
  float var = ss * (1.f / 512.f) - mu * mu;
  float inv = rsqrtf(var + CEPS);
  float f[8], s2 = 0.f, ss2 = 0.f;
  #pragma unroll
  for (int j = 0; j < 8; j++) {
    f[j] = (z[j] - mu) * inv * lng[c0 + j] + lnb[c0 + j];
    s2 += f[j]; ss2 += f[j] * f[j];
  }
  float4* fo = (float4*)(feats + (size_t)m * 512 + c0);
  fo[0] = make_float4(f[0], f[1], f[2], f[3]);
  fo[1] = make_float4(f[4], f[5], f[6], f[7]);
  #pragma unroll
  for (int off = 1; off < 64; off <<= 1) { s2 += __shfl_xor(s2, off, 64); ss2 += __shfl_xor(ss2, off, 64); }
  float mu2 = s2 * (1.f / 512.f);
  float var2 = ss2 * (1.f / 512.f) - mu2 * mu2;
  float inv2 = rsqrtf(var2 + CEPS);
  bf16x8 zv;
  #pragma unroll
  for (int j = 0; j < 8; j++) zv[j] = (bf16)((f[j] - mu2) * inv2);
  *(bf16x8*)(zhat + (size_t)m * 512 + c0) = zv;
}

// ---------------- finalize: s = row-sums of gw halves; softmax over T per path; pair, pooled
__global__ __launch_bounds__(256) void final_kernel(
    const bf16* __restrict__ gw, const float* __restrict__ feats,
    float* __restrict__ pair, float* __restrict__ pooled) {
  __shared__ float sE[32], sS[32], wmL[32];
  int b = blockIdx.x, tid = threadIdx.x;
  int lane = tid & 63, wv = tid >> 6;
  #pragma unroll
  for (int i = 0; i < 8; i++) {
    int t = wv * 8 + i;
    size_t m = (size_t)b * 32 + t;
    bf16x8 v8 = *(const bf16x8*)(gw + m * 512 + lane * 8);
    float s = 0.f;
    #pragma unroll
    for (int j = 0; j < 8; j++) s += (float)v8[j];
    #pragma unroll
    for (int off = 1; off < 32; off <<= 1) s += __shfl_xor(s, off, 64);
    if (lane == 0) sE[t] = s;    // lanes 0-31 covered cols 0-255 (ed)
    if (lane == 32) sS[t] = s;   // lanes 32-63 covered cols 256-511 (es)
  }
  __syncthreads();
  if (tid < 32) {
    float vE = sE[tid], vS = sS[tid];
    float mE = vE, mS = vS;
    #pragma unroll
    for (int off = 1; off < 32; off <<= 1) {
      mE = fmaxf(mE, __shfl_xor(mE, off, 32));
      mS = fmaxf(mS, __shfl_xor(mS, off, 32));
    }
    float eE = expf(vE - mE), eS = expf(vS - mS);
    float sumE = eE, sumS = eS;
    #pragma unroll
    for (int off = 1; off < 32; off <<= 1) {
      sumE += __shfl_xor(sumE, off, 32);
      sumS += __shfl_xor(sumS, off, 32);
    }
    float awE = eE / sumE, awS = eS / sumS;
    size_t pidx = ((size_t)b * 32 + tid) * 2;
    pair[pidx] = awE;
    pair[pidx + 1] = awS;
    wmL[tid] = 0.5f * (awE + awS);
  }
  __syncthreads();
  for (int c = tid; c < 512; c += 256) {
    float acc = 0.f;
    #pragma unroll
    for (int t = 0; t < 32; t++) acc += feats[((size_t)b * 32 + t) * 512 + c] * wmL[t];
    pooled[(size_t)b * 512 + c] = acc;
  }
}

extern "C" void kernel_launch(void* const* d_in, const int* in_sizes, int n_in,
                              void* d_out, int out_size, void* d_ws, size_t ws_size,
                              hipStream_t stream) {
  const float* x     = (const float*)d_in[0];
  const float* pos   = (const float*)d_in[1];
  const float* w3    = (const float*)d_in[2];
  const float* bn3g  = (const float*)d_in[3];
  const float* bn3b  = (const float*)d_in[4];
  const float* bn3m  = (const float*)d_in[5];
  const float* bn3v  = (const float*)d_in[6];
  const float* w5    = (const float*)d_in[7];
  const float* bn5g  = (const float*)d_in[8];
  const float* bn5b  = (const float*)d_in[9];
  const float* bn5m  = (const float*)d_in[10];
  const float* bn5v  = (const float*)d_in[11];
  const float* wmix  = (const float*)d_in[12];
  const float* bnmg  = (const float*)d_in[13];
  const float* bnmb  = (const float*)d_in[14];
  const float* bnmm  = (const float*)d_in[15];
  const float* bnmv  = (const float*)d_in[16];
  const float* lng   = (const float*)d_in[17];
  const float* lnb   = (const float*)d_in[18];
  const float* edlng = (const float*)d_in[19];
  const float* edlnb = (const float*)d_in[20];
  const float* edw1  = (const float*)d_in[21];
  const float* edb1  = (const float*)d_in[22];
  const float* edw2  = (const float*)d_in[23];
  const float* eslng = (const float*)d_in[25];
  const float* eslnb = (const float*)d_in[26];
  const float* esw1  = (const float*)d_in[27];
  const float* esb1  = (const float*)d_in[28];
  const float* esw2  = (const float*)d_in[29];
  const float* ted   = (const float*)d_in[31];
  const float* tes   = (const float*)d_in[32];

  char* ws = (char*)d_ws;
  bf16* Acat  = (bf16*)ws;                        // 201,326,592 B
  bf16* ctx   = (bf16*)(ws + 201326592);          //  67,108,864 B
  bf16* zhat  = (bf16*)(ws + 268435456);          //  67,108,864 B
  bf16* wmixf = (bf16*)(ws + 335544320);          //   1,572,864 B
  bf16* w1f   = (bf16*)(ws + 337117184);          //     524,288 B
  float* b1f  = (float*)(ws + 337641472);         //       2,048 B
  bf16* gw    = (bf16*)ws;                        // alias Acat (dead after ln_kernel)

  float* feats  = (float*)d_out;
  float* pooled = feats + 33554432;   // B*T*C
  float* pair   = pooled + 1048576;   // + B*C

  fold_kernel<<<1024, 256, 0, stream>>>(wmix, bnmg, bnmv, edlng, edlnb, eslng, eslnb,
                                        edw1, esw1, edb1, esb1, wmixf, w1f, b1f);
  prep_kernel<<<NB, 512, 0, stream>>>(x, w3, bn3g, bn3b, bn3m, bn3v,
                                      w5, bn5g, bn5b, bn5m, bn5v, Acat);
  gemm_bt<0><<<(MROWS / BM) * (CDIM / BN), 256, 0, stream>>>(
      Acat, wmixf, ctx, MROWS, CDIM, K3C,
      bnmg, bnmb, bnmm, bnmv, nullptr, nullptr, nullptr, nullptr, nullptr);
  ln_kernel<<<MROWS / 4, 256, 0, stream>>>(Acat, ctx, pos, lng, lnb, feats, zhat);
  gemm_bt<1><<<(MROWS / BM) * (CDIM / BN), 256, 0, stream>>>(
      zhat, w1f, gw, MROWS, CDIM, CDIM,
      nullptr, nullptr, nullptr, nullptr, b1f, edw2, esw2, ted, tes);
  final_kernel<<<NB, 256, 0, stream>>>(gw, feats, pair, pooled);
}

// Round 2
// 435.306 us; speedup vs baseline: 1.0958x; 1.0958x over previous
//
#include <hip/hip_runtime.h>
#include <cstdint>

typedef __bf16 bf16;
typedef __attribute__((ext_vector_type(8))) __bf16 bf16x8;
typedef __attribute__((ext_vector_type(4))) float f32x4;

#define CEPS 1e-5f
#define MROWS 65536   // B*T
#define NB 2048       // B
#define CDIM 512
#define K3C 1536

__device__ __forceinline__ float gelu_f(float x) {
  return 0.5f * x * (1.0f + erff(x * 0.70710678118654752440f));
}

__device__ __forceinline__ void gload_lds16(const void* g, void* l) {
  using GP = const __attribute__((address_space(1))) void*;
  using LP = __attribute__((address_space(3))) void*;
  __builtin_amdgcn_global_load_lds(reinterpret_cast<GP>(reinterpret_cast<uintptr_t>(g)),
                                   reinterpret_cast<LP>(reinterpret_cast<uintptr_t>(l)),
                                   16, 0, 0);
}

// ---------------- fold kernel (unchanged from r1)
__global__ __launch_bounds__(256) void fold_kernel(
    const float* __restrict__ wmix, const float* __restrict__ bnm_g, const float* __restrict__ bnm_v,
    const float* __restrict__ edg, const float* __restrict__ edb,
    const float* __restrict__ esg, const float* __restrict__ esb,
    const float* __restrict__ w1a, const float* __restrict__ w1b,
    const float* __restrict__ b1a, const float* __restrict__ b1b,
    bf16* __restrict__ wmixf, bf16* __restrict__ w1f, float* __restrict__ b1f) {
  __shared__ float red[4];
  int bid = blockIdx.x, tid = threadIdx.x;
  if (bid < 512) {
    int o = bid;
    float s = bnm_g[o] * rsqrtf(bnm_v[o] + CEPS);
    for (int c = tid; c < K3C; c += 256)
      wmixf[(size_t)o * K3C + c] = (bf16)(wmix[(size_t)o * K3C + c] * s);
  } else {
    int n = bid - 512;
    int half = (n < 256) ? 0 : 1;
    const float* g  = half ? esg : edg;
    const float* lb = half ? esb : edb;
    const float* w1 = half ? w1b : w1a;
    const float* b1 = half ? b1b : b1a;
    int nn = n & 255;
    float dot = 0.f;
    for (int c = tid; c < 512; c += 256) {
      float w = w1[(size_t)nn * 512 + c];
      w1f[(size_t)n * 512 + c] = (bf16)(w * g[c]);
      dot += w * lb[c];
    }
    #pragma unroll
    for (int off = 1; off < 64; off <<= 1) dot += __shfl_xor(dot, off, 64);
    if ((tid & 63) == 0) red[tid >> 6] = dot;
    __syncthreads();
    if (tid == 0) b1f[n] = b1[nn] + red[0] + red[1] + red[2] + red[3];
  }
}

// ---------------- prep (unchanged from r1)
__global__ __launch_bounds__(512) void prep_kernel(
    const float* __restrict__ x,
    const float* __restrict__ w3, const float* __restrict__ bn3g, const float* __restrict__ bn3b,
    const float* __restrict__ bn3m, const float* __restrict__ bn3v,
    const float* __restrict__ w5, const float* __restrict__ bn5g, const float* __restrict__ bn5b,
    const float* __restrict__ bn5m, const float* __restrict__ bn5v,
    bf16* __restrict__ Acat) {
  int b = blockIdx.x, c = threadIdx.x;
  const float4* xp = (const float4*)(x + ((size_t)b * 512 + c) * 64);
  float tf[32];
  #pragma unroll
  for (int i = 0; i < 16; i++) {
    float4 v = xp[i];
    tf[2 * i]     = 0.5f * (v.x + v.y);
    tf[2 * i + 1] = 0.5f * (v.z + v.w);
  }
  float s3 = bn3g[c] * rsqrtf(bn3v[c] + CEPS), t3 = bn3b[c] - bn3m[c] * s3;
  float s5 = bn5g[c] * rsqrtf(bn5v[c] + CEPS), t5 = bn5b[c] - bn5m[c] * s5;
  float w30 = w3[c * 3], w31 = w3[c * 3 + 1], w32 = w3[c * 3 + 2];
  float w50 = w5[c * 5], w51 = w5[c * 5 + 1], w52 = w5[c * 5 + 2], w53 = w5[c * 5 + 3], w54 = w5[c * 5 + 4];
  bf16* Ab = Acat + (size_t)b * 32 * K3C + c;
  #pragma unroll
  for (int t = 0; t < 32; t++) {
    float tm2 = (t >= 2) ? tf[t - 2] : 0.f;
    float tm1 = (t >= 1) ? tf[t - 1] : 0.f;
    float tp1 = (t < 31) ? tf[t + 1] : 0.f;
    float tp2 = (t < 30) ? tf[t + 2] : 0.f;
    float c3 = gelu_f((w30 * tm1 + w31 * tf[t] + w32 * tp1) * s3 + t3);
    float c5 = gelu_f((w50 * tm2 + w51 * tm1 + w52 * tf[t] + w53 * tp1 + w54 * tp2) * s5 + t5);
    Ab[t * K3C]        = (bf16)tf[t];
    Ab[t * K3C + 512]  = (bf16)c3;
    Ab[t * K3C + 1024] = (bf16)c5;
  }
}

// ---------------- 8-phase 256x256 GEMM (HK-style schedule, plain HIP)
// out[m,n] = epi( sum_k A[m,k]*B[n,k] ); A: MxK bf16 row-major, B: NxK bf16 row-major
// EPI 0: out = gelu(acc + bn_shift[n])   (mix -> ctx)
// EPI 1: no out write; s[m] = sum_n gelu(acc + b1f[n]) * (w2[n]/clip(temp))  (attn -> sE/sS)
#define GBM 256
#define GBN 256
#define GBK 64

__device__ __forceinline__ int xcd_swz(int bid, int nwg) {
  int q = nwg >> 3, r = nwg & 7;
  int xcd = bid & 7, i = bid >> 3;
  return (xcd < r ? xcd * (q + 1) : r * (q + 1) + (xcd - r) * q) + i;
}

#define BARRIER_SB()  do { __builtin_amdgcn_s_barrier(); __builtin_amdgcn_sched_barrier(0); } while (0)
#define LGKM0()       asm volatile("s_waitcnt lgkmcnt(0)" ::: "memory")

#define LOAD_A(q)                                                     \
  bf16x8 Af[2][2];                                                    \
  _Pragma("unroll")                                                   \
  for (int im = 0; im < 2; im++)                                      \
    _Pragma("unroll")                                                 \
    for (int k2 = 0; k2 < 2; k2++)                                    \
      Af[im][k2] = ldA(s, 2 * (q) + im, k2 * 32);

#define MFMA_Q(q)                                                     \
  __builtin_amdgcn_s_setprio(1);                                      \
  _Pragma("unroll")                                                   \
  for (int k2 = 0; k2 < 2; k2++)                                      \
    _Pragma("unroll")                                                 \
    for (int im = 0; im < 2; im++)                                    \
      _Pragma("unroll")                                               \
      for (int nr = 0; nr < 4; nr++)                                  \
        acc[2 * (q) + im][nr] = __builtin_amdgcn_mfma_f32_16x16x32_bf16( \
            Af[im][k2], Bf[nr][k2], acc[2 * (q) + im][nr], 0, 0, 0);  \
  __builtin_amdgcn_s_setprio(0);

template <int EPI, int KC>
__global__ __launch_bounds__(512, 2) void gemm8(
    const bf16* __restrict__ A, const bf16* __restrict__ Bm, bf16* __restrict__ out,
    float* __restrict__ sE, float* __restrict__ sS,
    const float* __restrict__ bn_g, const float* __restrict__ bn_b,
    const float* __restrict__ bn_m, const float* __restrict__ bn_v,
    const float* __restrict__ b1f,
    const float* __restrict__ w2a, const float* __restrict__ w2b,
    const float* __restrict__ ta, const float* __restrict__ tb) {
  __shared__ char lds[131072];   // 2 slots x (A 32KB + B 32KB)
  constexpr int KB = KC * 2;     // row bytes
  constexpr int kt = KC / GBK;
  int tid = threadIdx.x;
  int wv = tid >> 6, lane = tid & 63;
  int wm = wv >> 2, wn = wv & 3;       // 2 x 4 wave grid
  int fr = lane & 15, kq = lane >> 4;
  int wgid = xcd_swz(blockIdx.x, gridDim.x);
  int mb = wgid >> 1, nb = wgid & 1;   // nblk = 512/256 = 2

  const bf16* Ag = A + (size_t)mb * GBM * KC;
  const bf16* Bg = Bm + (size_t)nb * GBN * KC;

  // stage one 128-row half-tile: linear LDS dest, inverse-swizzled global source
  auto stage_half = [&](const bf16* Gsrc, int k0, int ldsoff) {
    #pragma unroll
    for (int l = 0; l < 2; l++) {
      int p = l * 8192 + tid * 16;
      int r = p >> 7;
      int sc = (p & 127) ^ ((r & 7) << 4);
      const char* g = (const char*)Gsrc + (size_t)r * KB + k0 * 2 + sc;
      gload_lds16(g, lds + ldsoff + l * 8192 + wv * 1024);
    }
  };
  // swizzled reads
  auto ldA = [&](int s, int mr, int kk) -> bf16x8 {
    int rr = mr * 16 + fr;
    int off = s * 65536 + wm * 16384 + ((rr * 128 + kk * 2 + kq * 16) ^ ((rr & 7) << 4));
    return *(const bf16x8*)(lds + off);
  };
  auto ldB = [&](int s, int nr, int kk) -> bf16x8 {
    int row = wn * 64 + nr * 16 + fr;
    int off = s * 65536 + 32768 + ((row >> 7) * 16384)
            + (((row & 127) * 128 + kk * 2 + kq * 16) ^ ((row & 7) << 4));
    return *(const bf16x8*)(lds + off);
  };

  const f32x4 fz = {0.f, 0.f, 0.f, 0.f};
  f32x4 acc[8][4];
  #pragma unroll
  for (int i = 0; i < 8; i++)
    #pragma unroll
    for (int j = 0; j < 4; j++) acc[i][j] = fz;

  // prologue: A(0),B(0) -> slot0; B(1) -> slot1; drain through B(0)
  stage_half(Ag,            0,   0);
  stage_half(Ag + 128 * KC, 0,   16384);
  stage_half(Bg,            0,   32768);
  stage_half(Bg + 128 * KC, 0,   49152);
  stage_half(Bg,            GBK, 65536 + 32768);
  stage_half(Bg + 128 * KC, GBK, 65536 + 49152);
  asm volatile("s_waitcnt vmcnt(4)" ::: "memory");
  BARRIER_SB();

  for (int t = 0; t < kt; t++) {
    int s = t & 1;
    bf16x8 Bf[4][2];
    // ---- phase 0: read all B + A-quad0; stage A-half0(t+1)
    if (t + 1 < kt) stage_half(Ag, (t + 1) * GBK, (s ^ 1) * 65536);
    #pragma unroll
    for (int nr = 0; nr < 4; nr++)
      #pragma unroll
      for (int k2 = 0; k2 < 2; k2++) Bf[nr][k2] = ldB(s, nr, k2 * 32);
    {
      LOAD_A(0);
      BARRIER_SB();
      MFMA_Q(0);
    }
    LGKM0();
    BARRIER_SB();
    // ---- phase 1: A-quad1; stage A-half1(t+1)
    if (t + 1 < kt) stage_half(Ag + 128 * KC, (t + 1) * GBK, (s ^ 1) * 65536 + 16384);
    {
      LOAD_A(1);
      BARRIER_SB();
      MFMA_Q(1);
    }
    LGKM0();
    BARRIER_SB();
    // ---- phase 2: A-quad2; stage B-half0(t+2)
    if (t + 2 < kt) stage_half(Bg, (t + 2) * GBK, s * 65536 + 32768);
    {
      LOAD_A(2);
      BARRIER_SB();
      MFMA_Q(2);
    }
    LGKM0();
    BARRIER_SB();
    // ---- phase 3: A-quad3; stage B-half1(t+2); counted vmcnt once per K-tile
    if (t + 2 < kt) stage_half(Bg + 128 * KC, (t + 2) * GBK, s * 65536 + 49152);
    {
      LOAD_A(3);
      BARRIER_SB();
      MFMA_Q(3);
    }
    if (t < kt - 2) {
      asm volatile("s_waitcnt vmcnt(4)" ::: "memory");   // next tile's A+B complete
    } else if (t == kt - 2) {
      asm volatile("s_waitcnt vmcnt(0)" ::: "memory");   // epilogue of pipeline
    }
    LGKM0();
    BARRIER_SB();
  }

  if constexpr (EPI == 0) {
    #pragma unroll
    for (int nr = 0; nr < 4; nr++) {
      int n = nb * GBN + wn * 64 + nr * 16 + fr;
      float sc = bn_g[n] * rsqrtf(bn_v[n] + CEPS);
      float bias = bn_b[n] - bn_m[n] * sc;
      #pragma unroll
      for (int mr = 0; mr < 8; mr++)
        #pragma unroll
        for (int j = 0; j < 4; j++) {
          size_t m = (size_t)mb * GBM + wm * 128 + mr * 16 + kq * 4 + j;
          out[m * CDIM + n] = (bf16)gelu_f(acc[mr][nr][j] + bias);
        }
    }
  } else {
    // fused row-reduction: s[m] = sum_n gelu(acc + b1f[n]) * w2s[n]
    float bias[4], w2s[4];
    #pragma unroll
    for (int nr = 0; nr < 4; nr++) {
      int n = nb * GBN + wn * 64 + nr * 16 + fr;
      bias[nr] = b1f[n];
      float tv = (n < 256) ? ta[0] : tb[0];
      tv = fminf(fmaxf(tv, 0.25f), 4.0f);
      w2s[nr] = ((n < 256) ? w2a[n] : w2b[n - 256]) / tv;
    }
    float* sred = (float*)lds;   // [4 wn][256 rows]
    __syncthreads();
    #pragma unroll
    for (int mr = 0; mr < 8; mr++) {
      float p0 = 0.f, p1 = 0.f, p2 = 0.f, p3 = 0.f;
      #pragma unroll
      for (int nr = 0; nr < 4; nr++) {
        p0 += gelu_f(acc[mr][nr][0] + bias[nr]) * w2s[nr];
        p1 += gelu_f(acc[mr][nr][1] + bias[nr]) * w2s[nr];
        p2 += gelu_f(acc[mr][nr][2] + bias[nr]) * w2s[nr];
        p3 += gelu_f(acc[mr][nr][3] + bias[nr]) * w2s[nr];
      }
      #pragma unroll
      for (int off = 1; off < 16; off <<= 1) {
        p0 += __shfl_xor(p0, off, 64);
        p1 += __shfl_xor(p1, off, 64);
        p2 += __shfl_xor(p2, off, 64);
        p3 += __shfl_xor(p3, off, 64);
      }
      if (fr == 0) {
        int rbase = wm * 128 + mr * 16 + kq * 4;
        sred[wn * 256 + rbase]     = p0;
        sred[wn * 256 + rbase + 1] = p1;
        sred[wn * 256 + rbase + 2] = p2;
        sred[wn * 256 + rbase + 3] = p3;
      }
    }
    __syncthreads();
    if (tid < 256) {
      float sv = sred[tid] + sred[256 + tid] + sred[512 + tid] + sred[768 + tid];
      float* so = nb ? sS : sE;
      so[(size_t)mb * GBM + tid] = sv;
    }
  }
}

// ---------------- LN: z = tf + ctx + pos; feats = LN(z)*g+b (f32); zhat = standardize(feats) bf16
__global__ __launch_bounds__(256) void ln_kernel(
    const bf16* __restrict__ Acat, const bf16* __restrict__ ctx, const float* __restrict__ pos,
    const float* __restrict__ lng, const float* __restrict__ lnb,
    float* __restrict__ feats, bf16* __restrict__ zhat) {
  int m = blockIdx.x * 4 + (threadIdx.x >> 6);
  int lane = threadIdx.x & 63;
  int c0 = lane * 8;
  int t = m & 31;
  bf16x8 tf8 = *(const bf16x8*)(Acat + (size_t)m * K3C + c0);
  bf16x8 cx8 = *(const bf16x8*)(ctx + (size_t)m * 512 + c0);
  const float* pp = pos + t * 512 + c0;
  float z[8], s = 0.f, ss = 0.f;
  #pragma unroll
  for (int j = 0; j < 8; j++) {
    z[j] = (float)tf8[j] + (float)cx8[j] + pp[j];
    s += z[j]; ss += z[j] * z[j];
  }
  #pragma unroll
  for (int off = 1; off < 64; off <<= 1) { s += __shfl_xor(s, off, 64); ss += __shfl_xor(ss, off, 64); }
  float mu = s * (1.f / 512.f);
  float var = ss * (1.f / 512.f) - mu * mu;
  float inv = rsqrtf(var + CEPS);
  float f[8], s2 = 0.f, ss2 = 0.f;
  #pragma unroll
  for (int j = 0; j < 8; j++) {
    f[j] = (z[j] - mu) * inv * lng[c0 + j] + lnb[c0 + j];
    s2 += f[j]; ss2 += f[j] * f[j];
  }
  float4* fo = (float4*)(feats + (size_t)m * 512 + c0);
  fo[0] = make_float4(f[0], f[1], f[2], f[3]);
  fo[1] = make_float4(f[4], f[5], f[6], f[7]);
  #pragma unroll
  for (int off = 1; off < 64; off <<= 1) { s2 += __shfl_xor(s2, off, 64); ss2 += __shfl_xor(ss2, off, 64); }
  float mu2 = s2 * (1.f / 512.f);
  float var2 = ss2 * (1.f / 512.f) - mu2 * mu2;
  float inv2 = rsqrtf(var2 + CEPS);
  bf16x8 zv;
  #pragma unroll
  for (int j = 0; j < 8; j++) zv[j] = (bf16)((f[j] - mu2) * inv2);
  *(bf16x8*)(zhat + (size_t)m * 512 + c0) = zv;
}

// ---------------- finalize: softmax over T per path from sE/sS; pair, pooled
__global__ __launch_bounds__(256) void final_kernel(
    const float* __restrict__ sE, const float* __restrict__ sS,
    const float* __restrict__ feats, float* __restrict__ pair, float* __restrict__ pooled) {
  __shared__ float wmL[32];
  int b = blockIdx.x, tid = threadIdx.x;
  if (tid < 32) {
    float vE = sE[(size_t)b * 32 + tid], vS = sS[(size_t)b * 32 + tid];
    float mE = vE, mS = vS;
    #pragma unroll
    for (int off = 1; off < 32; off <<= 1) {
      mE = fmaxf(mE, __shfl_xor(mE, off, 32));
      mS = fmaxf(mS, __shfl_xor(mS, off, 32));
    }
    float eE = expf(vE - mE), eS = expf(vS - mS);
    float sumE = eE, sumS = eS;
    #pragma unroll
    for (int off = 1; off < 32; off <<= 1) {
      sumE += __shfl_xor(sumE, off, 32);
      sumS += __shfl_xor(sumS, off, 32);
    }
    float awE = eE / sumE, awS = eS / sumS;
    size_t pidx = ((size_t)b * 32 + tid) * 2;
    pair[pidx] = awE;
    pair[pidx + 1] = awS;
    wmL[tid] = 0.5f * (awE + awS);
  }
  __syncthreads();
  {
    int c = tid * 2;
    float a0 = 0.f, a1 = 0.f;
    #pragma unroll
    for (int t = 0; t < 32; t++) {
      float2 v = *(const float2*)&feats[((size_t)b * 32 + t) * 512 + c];
      float w = wmL[t];
      a0 += v.x * w; a1 += v.y * w;
    }
    *(float2*)&pooled[(size_t)b * 512 + c] = make_float2(a0, a1);
  }
}

extern "C" void kernel_launch(void* const* d_in, const int* in_sizes, int n_in,
                              void* d_out, int out_size, void* d_ws, size_t ws_size,
                              hipStream_t stream) {
  const float* x     = (const float*)d_in[0];
  const float* pos   = (const float*)d_in[1];
  const float* w3    = (const float*)d_in[2];
  const float* bn3g  = (const float*)d_in[3];
  const float* bn3b  = (const float*)d_in[4];
  const float* bn3m  = (const float*)d_in[5];
  const float* bn3v  = (const float*)d_in[6];
  const float* w5    = (const float*)d_in[7];
  const float* bn5g  = (const float*)d_in[8];
  const float* bn5b  = (const float*)d_in[9];
  const float* bn5m  = (const float*)d_in[10];
  const float* bn5v  = (const float*)d_in[11];
  const float* wmix  = (const float*)d_in[12];
  const float* bnmg  = (const float*)d_in[13];
  const float* bnmb  = (const float*)d_in[14];
  const float* bnmm  = (const float*)d_in[15];
  const float* bnmv  = (const float*)d_in[16];
  const float* lng   = (const float*)d_in[17];
  const float* lnb   = (const float*)d_in[18];
  const float* edlng = (const float*)d_in[19];
  const float* edlnb = (const float*)d_in[20];
  const float* edw1  = (const float*)d_in[21];
  const float* edb1  = (const float*)d_in[22];
  const float* edw2  = (const float*)d_in[23];
  const float* eslng = (const float*)d_in[25];
  const float* eslnb = (const float*)d_in[26];
  const float* esw1  = (const float*)d_in[27];
  const float* esb1  = (const float*)d_in[28];
  const float* esw2  = (const float*)d_in[29];
  const float* ted   = (const float*)d_in[31];
  const float* tes   = (const float*)d_in[32];

  char* ws = (char*)d_ws;
  bf16* Acat  = (bf16*)ws;                        // 201,326,592 B
  bf16* ctx   = (bf16*)(ws + 201326592);          //  67,108,864 B
  bf16* zhat  = (bf16*)(ws + 268435456);          //  67,108,864 B
  bf16* wmixf = (bf16*)(ws + 335544320);          //   1,572,864 B
  bf16* w1f   = (bf16*)(ws + 337117184);          //     524,288 B
  float* b1f  = (float*)(ws + 337641472);         //       2,048 B
  // sE/sS alias Acat (dead after ln_kernel; attn gemm reads zhat only)
  float* sEb  = (float*)ws;                       // 262,144 B
  float* sSb  = (float*)(ws + 262144);            // 262,144 B

  float* feats  = (float*)d_out;
  float* pooled = feats + 33554432;   // B*T*C
  float* pair   = pooled + 1048576;   // + B*C

  fold_kernel<<<1024, 256, 0, stream>>>(wmix, bnmg, bnmv, edlng, edlnb, eslng, eslnb,
                                        edw1, esw1, edb1, esb1, wmixf, w1f, b1f);
  prep_kernel<<<NB, 512, 0, stream>>>(x, w3, bn3g, bn3b, bn3m, bn3v,
                                      w5, bn5g, bn5b, bn5m, bn5v, Acat);
  gemm8<0, K3C><<<(MROWS / GBM) * (CDIM / GBN), 512, 0, stream>>>(
      Acat, wmixf, ctx, nullptr, nullptr,
      bnmg, bnmb, bnmm, bnmv, nullptr, nullptr, nullptr, nullptr, nullptr);
  ln_kernel<<<MROWS / 4, 256, 0, stream>>>(Acat, ctx, pos, lng, lnb, feats, zhat);
  gemm8<1, CDIM><<<(MROWS / GBM) * (CDIM / GBN), 512, 0, stream>>>(
      zhat, w1f, nullptr, sEb, sSb,
      nullptr, nullptr, nullptr, nullptr, b1f, edw2, esw2, ted, tes);
  final_kernel<<<NB, 256, 0, stream>>>(sEb, sSb, feats, pair, pooled);
}

// Round 3
// 407.745 us; speedup vs baseline: 1.1699x; 1.0676x over previous
//
#include <hip/hip_runtime.h>
#include <cstdint>

typedef __bf16 bf16;
typedef __attribute__((ext_vector_type(8))) __bf16 bf16x8;
typedef __attribute__((ext_vector_type(4))) float f32x4;

#define CEPS 1e-5f
#define MROWS 65536   // B*T
#define NB 2048       // B
#define CDIM 512
#define K3C 1536

// fast gelu: tanh form via native exp; |err| <= ~3e-3 absolute, well under bf16 rounding here
__device__ __forceinline__ float gelu_f(float x) {
  float x2 = x * x;
  float u = x * (0.7978845608f + 0.0356774081f * x2);   // sqrt(2/pi)*(x+0.044715x^3)
  float e = __expf(2.0f * u);
  float th = 1.0f - __fdividef(2.0f, e + 1.0f);          // tanh(u)
  return 0.5f * x * (1.0f + th);
}

__device__ __forceinline__ void gload_lds16(const void* g, void* l) {
  using GP = const __attribute__((address_space(1))) void*;
  using LP = __attribute__((address_space(3))) void*;
  __builtin_amdgcn_global_load_lds(reinterpret_cast<GP>(reinterpret_cast<uintptr_t>(g)),
                                   reinterpret_cast<LP>(reinterpret_cast<uintptr_t>(l)),
                                   16, 0, 0);
}

// ---------------- fold kernel
__global__ __launch_bounds__(256) void fold_kernel(
    const float* __restrict__ wmix, const float* __restrict__ bnm_g, const float* __restrict__ bnm_v,
    const float* __restrict__ edg, const float* __restrict__ edb,
    const float* __restrict__ esg, const float* __restrict__ esb,
    const float* __restrict__ w1a, const float* __restrict__ w1b,
    const float* __restrict__ b1a, const float* __restrict__ b1b,
    bf16* __restrict__ wmixf, bf16* __restrict__ w1f, float* __restrict__ b1f) {
  __shared__ float red[4];
  int bid = blockIdx.x, tid = threadIdx.x;
  if (bid < 512) {
    int o = bid;
    float s = bnm_g[o] * rsqrtf(bnm_v[o] + CEPS);
    for (int c = tid; c < K3C; c += 256)
      wmixf[(size_t)o * K3C + c] = (bf16)(wmix[(size_t)o * K3C + c] * s);
  } else {
    int n = bid - 512;
    int half = (n < 256) ? 0 : 1;
    const float* g  = half ? esg : edg;
    const float* lb = half ? esb : edb;
    const float* w1 = half ? w1b : w1a;
    const float* b1 = half ? b1b : b1a;
    int nn = n & 255;
    float dot = 0.f;
    for (int c = tid; c < 512; c += 256) {
      float w = w1[(size_t)nn * 512 + c];
      w1f[(size_t)n * 512 + c] = (bf16)(w * g[c]);
      dot += w * lb[c];
    }
    #pragma unroll
    for (int off = 1; off < 64; off <<= 1) dot += __shfl_xor(dot, off, 64);
    if ((tid & 63) == 0) red[tid >> 6] = dot;
    __syncthreads();
    if (tid == 0) b1f[n] = b1[nn] + red[0] + red[1] + red[2] + red[3];
  }
}

// ---------------- prep: x[b,c,64] -> tf, c3, c5 -> Acat[(b*32+t), {c, 512+c, 1024+c}] bf16
__global__ __launch_bounds__(512) void prep_kernel(
    const float* __restrict__ x,
    const float* __restrict__ w3, const float* __restrict__ bn3g, const float* __restrict__ bn3b,
    const float* __restrict__ bn3m, const float* __restrict__ bn3v,
    const float* __restrict__ w5, const float* __restrict__ bn5g, const float* __restrict__ bn5b,
    const float* __restrict__ bn5m, const float* __restrict__ bn5v,
    bf16* __restrict__ Acat) {
  int b = blockIdx.x, c = threadIdx.x;
  const float4* xp = (const float4*)(x + ((size_t)b * 512 + c) * 64);
  float tf[32];
  #pragma unroll
  for (int i = 0; i < 16; i++) {
    float4 v = xp[i];
    tf[2 * i]     = 0.5f * (v.x + v.y);
    tf[2 * i + 1] = 0.5f * (v.z + v.w);
  }
  float s3 = bn3g[c] * rsqrtf(bn3v[c] + CEPS), t3 = bn3b[c] - bn3m[c] * s3;
  float s5 = bn5g[c] * rsqrtf(bn5v[c] + CEPS), t5 = bn5b[c] - bn5m[c] * s5;
  float w30 = w3[c * 3], w31 = w3[c * 3 + 1], w32 = w3[c * 3 + 2];
  float w50 = w5[c * 5], w51 = w5[c * 5 + 1], w52 = w5[c * 5 + 2], w53 = w5[c * 5 + 3], w54 = w5[c * 5 + 4];
  bf16* Ab = Acat + (size_t)b * 32 * K3C + c;
  #pragma unroll
  for (int t = 0; t < 32; t++) {
    float tm2 = (t >= 2) ? tf[t - 2] : 0.f;
    float tm1 = (t >= 1) ? tf[t - 1] : 0.f;
    float tp1 = (t < 31) ? tf[t + 1] : 0.f;
    float tp2 = (t < 30) ? tf[t + 2] : 0.f;
    float c3 = gelu_f((w30 * tm1 + w31 * tf[t] + w32 * tp1) * s3 + t3);
    float c5 = gelu_f((w50 * tm2 + w51 * tm1 + w52 * tf[t] + w53 * tp1 + w54 * tp2) * s5 + t5);
    Ab[t * K3C]        = (bf16)tf[t];
    Ab[t * K3C + 512]  = (bf16)c3;
    Ab[t * K3C + 1024] = (bf16)c5;
  }
}

// ---------------- 8-phase 256x256 GEMM (HK-style schedule, plain HIP)
// out[m,n] = epi( sum_k A[m,k]*B[n,k] ); A: MxK bf16 row-major, B: NxK bf16 row-major
// EPI 0: out = gelu(acc + bn_shift[n])   (mix -> ctx)
// EPI 1: no out write; s[m] = sum_n gelu(acc + b1f[n]) * (w2[n]/clip(temp))  (attn -> sE/sS)
#define GBM 256
#define GBN 256
#define GBK 64

__device__ __forceinline__ int xcd_swz(int bid, int nwg) {
  int q = nwg >> 3, r = nwg & 7;
  int xcd = bid & 7, i = bid >> 3;
  return (xcd < r ? xcd * (q + 1) : r * (q + 1) + (xcd - r) * q) + i;
}

#define BARRIER_SB()  do { __builtin_amdgcn_s_barrier(); __builtin_amdgcn_sched_barrier(0); } while (0)

#define LOAD_A(q)                                                     \
  bf16x8 Af[2][2];                                                    \
  _Pragma("unroll")                                                   \
  for (int im = 0; im < 2; im++)                                      \
    _Pragma("unroll")                                                 \
    for (int k2 = 0; k2 < 2; k2++)                                    \
      Af[im][k2] = ldA(s, 2 * (q) + im, k2 * 32);

#define MFMA_Q(q)                                                     \
  __builtin_amdgcn_s_setprio(1);                                      \
  _Pragma("unroll")                                                   \
  for (int k2 = 0; k2 < 2; k2++)                                      \
    _Pragma("unroll")                                                 \
    for (int im = 0; im < 2; im++)                                    \
      _Pragma("unroll")                                               \
      for (int nr = 0; nr < 4; nr++)                                  \
        acc[2 * (q) + im][nr] = __builtin_amdgcn_mfma_f32_16x16x32_bf16( \
            Af[im][k2], Bf[nr][k2], acc[2 * (q) + im][nr], 0, 0, 0);  \
  __builtin_amdgcn_s_setprio(0);

template <int EPI, int KC>
__global__ __launch_bounds__(512, 2) void gemm8(
    const bf16* __restrict__ A, const bf16* __restrict__ Bm, bf16* __restrict__ out,
    float* __restrict__ sE, float* __restrict__ sS,
    const float* __restrict__ bn_g, const float* __restrict__ bn_b,
    const float* __restrict__ bn_m, const float* __restrict__ bn_v,
    const float* __restrict__ b1f,
    const float* __restrict__ w2a, const float* __restrict__ w2b,
    const float* __restrict__ ta, const float* __restrict__ tb) {
  __shared__ char lds[131072];   // 2 slots x (A 32KB + B 32KB)
  constexpr int KB = KC * 2;     // row bytes
  constexpr int kt = KC / GBK;
  int tid = threadIdx.x;
  int wv = tid >> 6, lane = tid & 63;
  int wm = wv >> 2, wn = wv & 3;       // 2 x 4 wave grid
  int fr = lane & 15, kq = lane >> 4;
  int wgid = xcd_swz(blockIdx.x, gridDim.x);
  int mb = wgid >> 1, nb = wgid & 1;   // nblk = 512/256 = 2

  const bf16* Ag = A + (size_t)mb * GBM * KC;
  const bf16* Bg = Bm + (size_t)nb * GBN * KC;

  // stage one 128-row half-tile: linear LDS dest, inverse-swizzled global source
  auto stage_half = [&](const bf16* Gsrc, int k0, int ldsoff) {
    #pragma unroll
    for (int l = 0; l < 2; l++) {
      int p = l * 8192 + tid * 16;
      int r = p >> 7;
      int sc = (p & 127) ^ ((r & 7) << 4);
      const char* g = (const char*)Gsrc + (size_t)r * KB + k0 * 2 + sc;
      gload_lds16(g, lds + ldsoff + l * 8192 + wv * 1024);
    }
  };
  // swizzled reads
  auto ldA = [&](int s, int mr, int kk) -> bf16x8 {
    int rr = mr * 16 + fr;
    int off = s * 65536 + wm * 16384 + ((rr * 128 + kk * 2 + kq * 16) ^ ((rr & 7) << 4));
    return *(const bf16x8*)(lds + off);
  };
  auto ldB = [&](int s, int nr, int kk) -> bf16x8 {
    int row = wn * 64 + nr * 16 + fr;
    int off = s * 65536 + 32768 + ((row >> 7) * 16384)
            + (((row & 127) * 128 + kk * 2 + kq * 16) ^ ((row & 7) << 4));
    return *(const bf16x8*)(lds + off);
  };

  const f32x4 fz = {0.f, 0.f, 0.f, 0.f};
  f32x4 acc[8][4];
  #pragma unroll
  for (int i = 0; i < 8; i++)
    #pragma unroll
    for (int j = 0; j < 4; j++) acc[i][j] = fz;

  // prologue: A(0),B(0) -> slot0; B(1) -> slot1; drain through B(0)
  stage_half(Ag,            0,   0);
  stage_half(Ag + 128 * KC, 0,   16384);
  stage_half(Bg,            0,   32768);
  stage_half(Bg + 128 * KC, 0,   49152);
  stage_half(Bg,            GBK, 65536 + 32768);
  stage_half(Bg + 128 * KC, GBK, 65536 + 49152);
  asm volatile("s_waitcnt vmcnt(4)" ::: "memory");
  BARRIER_SB();

  for (int t = 0; t < kt; t++) {
    int s = t & 1;
    bf16x8 Bf[4][2];
    // ---- phase 0: read all B + A-quad0; stage A-half0(t+1)
    if (t + 1 < kt) stage_half(Ag, (t + 1) * GBK, (s ^ 1) * 65536);
    #pragma unroll
    for (int nr = 0; nr < 4; nr++)
      #pragma unroll
      for (int k2 = 0; k2 < 2; k2++) Bf[nr][k2] = ldB(s, nr, k2 * 32);
    {
      LOAD_A(0);
      BARRIER_SB();
      MFMA_Q(0);
    }
    BARRIER_SB();
    // ---- phase 1: A-quad1; stage A-half1(t+1)
    if (t + 1 < kt) stage_half(Ag + 128 * KC, (t + 1) * GBK, (s ^ 1) * 65536 + 16384);
    {
      LOAD_A(1);
      BARRIER_SB();
      MFMA_Q(1);
    }
    BARRIER_SB();
    // ---- phase 2: A-quad2; stage B-half0(t+2)
    if (t + 2 < kt) stage_half(Bg, (t + 2) * GBK, s * 65536 + 32768);
    {
      LOAD_A(2);
      BARRIER_SB();
      MFMA_Q(2);
    }
    BARRIER_SB();
    // ---- phase 3: A-quad3; stage B-half1(t+2); counted vmcnt once per K-tile
    if (t + 2 < kt) stage_half(Bg + 128 * KC, (t + 2) * GBK, s * 65536 + 49152);
    {
      LOAD_A(3);
      BARRIER_SB();
      MFMA_Q(3);
    }
    if (t < kt - 2) {
      asm volatile("s_waitcnt vmcnt(4)" ::: "memory");   // next tile's A+B complete
    } else if (t == kt - 2) {
      asm volatile("s_waitcnt vmcnt(0)" ::: "memory");   // epilogue of pipeline
    }
    BARRIER_SB();
  }

  if constexpr (EPI == 0) {
    #pragma unroll
    for (int nr = 0; nr < 4; nr++) {
      int n = nb * GBN + wn * 64 + nr * 16 + fr;
      float sc = bn_g[n] * rsqrtf(bn_v[n] + CEPS);
      float bias = bn_b[n] - bn_m[n] * sc;
      #pragma unroll
      for (int mr = 0; mr < 8; mr++)
        #pragma unroll
        for (int j = 0; j < 4; j++) {
          size_t m = (size_t)mb * GBM + wm * 128 + mr * 16 + kq * 4 + j;
          out[m * CDIM + n] = (bf16)gelu_f(acc[mr][nr][j] + bias);
        }
    }
  } else {
    // fused row-reduction: s[m] = sum_n gelu(acc + b1f[n]) * w2s[n]
    float bias[4], w2s[4];
    #pragma unroll
    for (int nr = 0; nr < 4; nr++) {
      int n = nb * GBN + wn * 64 + nr * 16 + fr;
      bias[nr] = b1f[n];
      float tv = (n < 256) ? ta[0] : tb[0];
      tv = fminf(fmaxf(tv, 0.25f), 4.0f);
      w2s[nr] = ((n < 256) ? w2a[n] : w2b[n - 256]) / tv;
    }
    float* sred = (float*)lds;   // [4 wn][256 rows]
    __syncthreads();
    #pragma unroll
    for (int mr = 0; mr < 8; mr++) {
      float p0 = 0.f, p1 = 0.f, p2 = 0.f, p3 = 0.f;
      #pragma unroll
      for (int nr = 0; nr < 4; nr++) {
        p0 += gelu_f(acc[mr][nr][0] + bias[nr]) * w2s[nr];
        p1 += gelu_f(acc[mr][nr][1] + bias[nr]) * w2s[nr];
        p2 += gelu_f(acc[mr][nr][2] + bias[nr]) * w2s[nr];
        p3 += gelu_f(acc[mr][nr][3] + bias[nr]) * w2s[nr];
      }
      #pragma unroll
      for (int off = 1; off < 16; off <<= 1) {
        p0 += __shfl_xor(p0, off, 64);
        p1 += __shfl_xor(p1, off, 64);
        p2 += __shfl_xor(p2, off, 64);
        p3 += __shfl_xor(p3, off, 64);
      }
      if (fr == 0) {
        int rbase = wm * 128 + mr * 16 + kq * 4;
        sred[wn * 256 + rbase]     = p0;
        sred[wn * 256 + rbase + 1] = p1;
        sred[wn * 256 + rbase + 2] = p2;
        sred[wn * 256 + rbase + 3] = p3;
      }
    }
    __syncthreads();
    if (tid < 256) {
      float sv = sred[tid] + sred[256 + tid] + sred[512 + tid] + sred[768 + tid];
      float* so = nb ? sS : sE;
      so[(size_t)mb * GBM + tid] = sv;
    }
  }
}

// ---------------- LN: z = tf + ctx + pos; feats = LN(z)*g+b (f32); zhat = standardize(feats) bf16
__global__ __launch_bounds__(256) void ln_kernel(
    const bf16* __restrict__ Acat, const bf16* __restrict__ ctx, const float* __restrict__ pos,
    const float* __restrict__ lng, const float* __restrict__ lnb,
    float* __restrict__ feats, bf16* __restrict__ zhat) {
  int m = blockIdx.x * 4 + (threadIdx.x >> 6);
  int lane = threadIdx.x & 63;
  int c0 = lane * 8;
  int t = m & 31;
  bf16x8 tf8 = *(const bf16x8*)(Acat + (size_t)m * K3C + c0);
  bf16x8 cx8 = *(const bf16x8*)(ctx + (size_t)m * 512 + c0);
  const float* pp = pos + t * 512 + c0;
  float z[8], s = 0.f, ss = 0.f;
  #pragma unroll
  for (int j = 0; j < 8; j++) {
    z[j] = (float)tf8[j] + (float)cx8[j] + pp[j];
    s += z[j]; ss += z[j] * z[j];
  }
  #pragma unroll
  for (int off = 1; off < 64; off <<= 1) { s += __shfl_xor(s, off, 64); ss += __shfl_xor(ss, off, 64); }
  float mu = s * (1.f / 512.f);
  float var = ss * (1.f / 512.f) - mu * mu;
  float inv = rsqrtf(var + CEPS);
  float f[8], s2 = 0.f, ss2 = 0.f;
  #pragma unroll
  for (int j = 0; j < 8; j++) {
    f[j] = (z[j] - mu) * inv * lng[c0 + j] + lnb[c0 + j];
    s2 += f[j]; ss2 += f[j] * f[j];
  }
  float4* fo = (float4*)(feats + (size_t)m * 512 + c0);
  fo[0] = make_float4(f[0], f[1], f[2], f[3]);
  fo[1] = make_float4(f[4], f[5], f[6], f[7]);
  #pragma unroll
  for (int off = 1; off < 64; off <<= 1) { s2 += __shfl_xor(s2, off, 64); ss2 += __shfl_xor(ss2, off, 64); }
  float mu2 = s2 * (1.f / 512.f);
  float var2 = ss2 * (1.f / 512.f) - mu2 * mu2;
  float inv2 = rsqrtf(var2 + CEPS);
  bf16x8 zv;
  #pragma unroll
  for (int j = 0; j < 8; j++) zv[j] = (bf16)((f[j] - mu2) * inv2);
  *(bf16x8*)(zhat + (size_t)m * 512 + c0) = zv;
}

// ---------------- finalize: softmax over T per path from sE/sS; pair, pooled
__global__ __launch_bounds__(256) void final_kernel(
    const float* __restrict__ sE, const float* __restrict__ sS,
    const float* __restrict__ feats, float* __restrict__ pair, float* __restrict__ pooled) {
  __shared__ float wmL[32];
  int b = blockIdx.x, tid = threadIdx.x;
  if (tid < 32) {
    float vE = sE[(size_t)b * 32 + tid], vS = sS[(size_t)b * 32 + tid];
    float mE = vE, mS = vS;
    #pragma unroll
    for (int off = 1; off < 32; off <<= 1) {
      mE = fmaxf(mE, __shfl_xor(mE, off, 32));
      mS = fmaxf(mS, __shfl_xor(mS, off, 32));
    }
    float eE = expf(vE - mE), eS = expf(vS - mS);
    float sumE = eE, sumS = eS;
    #pragma unroll
    for (int off = 1; off < 32; off <<= 1) {
      sumE += __shfl_xor(sumE, off, 32);
      sumS += __shfl_xor(sumS, off, 32);
    }
    float awE = eE / sumE, awS = eS / sumS;
    size_t pidx = ((size_t)b * 32 + tid) * 2;
    pair[pidx] = awE;
    pair[pidx + 1] = awS;
    wmL[tid] = 0.5f * (awE + awS);
  }
  __syncthreads();
  {
    int c = tid * 2;
    float a0 = 0.f, a1 = 0.f;
    #pragma unroll
    for (int t = 0; t < 32; t++) {
      float2 v = *(const float2*)&feats[((size_t)b * 32 + t) * 512 + c];
      float w = wmL[t];
      a0 += v.x * w; a1 += v.y * w;
    }
    *(float2*)&pooled[(size_t)b * 512 + c] = make_float2(a0, a1);
  }
}

extern "C" void kernel_launch(void* const* d_in, const int* in_sizes, int n_in,
                              void* d_out, int out_size, void* d_ws, size_t ws_size,
                              hipStream_t stream) {
  const float* x     = (const float*)d_in[0];
  const float* pos   = (const float*)d_in[1];
  const float* w3    = (const float*)d_in[2];
  const float* bn3g  = (const float*)d_in[3];
  const float* bn3b  = (const float*)d_in[4];
  const float* bn3m  = (const float*)d_in[5];
  const float* bn3v  = (const float*)d_in[6];
  const float* w5    = (const float*)d_in[7];
  const float* bn5g  = (const float*)d_in[8];
  const float* bn5b  = (const float*)d_in[9];
  const float* bn5m  = (const float*)d_in[10];
  const float* bn5v  = (const float*)d_in[11];
  const float* wmix  = (const float*)d_in[12];
  const float* bnmg  = (const float*)d_in[13];
  const float* bnmb  = (const float*)d_in[14];
  const float* bnmm  = (const float*)d_in[15];
  const float* bnmv  = (const float*)d_in[16];
  const float* lng   = (const float*)d_in[17];
  const float* lnb   = (const float*)d_in[18];
  const float* edlng = (const float*)d_in[19];
  const float* edlnb = (const float*)d_in[20];
  const float* edw1  = (const float*)d_in[21];
  const float* edb1  = (const float*)d_in[22];
  const float* edw2  = (const float*)d_in[23];
  const float* eslng = (const float*)d_in[25];
  const float* eslnb = (const float*)d_in[26];
  const float* esw1  = (const float*)d_in[27];
  const float* esb1  = (const float*)d_in[28];
  const float* esw2  = (const float*)d_in[29];
  const float* ted   = (const float*)d_in[31];
  const float* tes   = (const float*)d_in[32];

  char* ws = (char*)d_ws;
  bf16* Acat  = (bf16*)ws;                        // 201,326,592 B
  bf16* ctx   = (bf16*)(ws + 201326592);          //  67,108,864 B
  bf16* zhat  = (bf16*)(ws + 268435456);          //  67,108,864 B
  bf16* wmixf = (bf16*)(ws + 335544320);          //   1,572,864 B
  bf16* w1f   = (bf16*)(ws + 337117184);          //     524,288 B
  float* b1f  = (float*)(ws + 337641472);         //       2,048 B
  // sE/sS alias Acat (dead after ln_kernel; attn gemm reads zhat only)
  float* sEb  = (float*)ws;                       // 262,144 B
  float* sSb  = (float*)(ws + 262144);            // 262,144 B

  float* feats  = (float*)d_out;
  float* pooled = feats + 33554432;   // B*T*C
  float* pair   = pooled + 1048576;   // + B*C

  fold_kernel<<<1024, 256, 0, stream>>>(wmix, bnmg, bnmv, edlng, edlnb, eslng, eslnb,
                                        edw1, esw1, edb1, esb1, wmixf, w1f, b1f);
  prep_kernel<<<NB, 512, 0, stream>>>(x, w3, bn3g, bn3b, bn3m, bn3v,
                                      w5, bn5g, bn5b, bn5m, bn5v, Acat);
  gemm8<0, K3C><<<(MROWS / GBM) * (CDIM / GBN), 512, 0, stream>>>(
      Acat, wmixf, ctx, nullptr, nullptr,
      bnmg, bnmb, bnmm, bnmv, nullptr, nullptr, nullptr, nullptr, nullptr);
  ln_kernel<<<MROWS / 4, 256, 0, stream>>>(Acat, ctx, pos, lng, lnb, feats, zhat);
  gemm8<1, CDIM><<<(MROWS / GBM) * (CDIM / GBN), 512, 0, stream>>>(
      zhat, w1f, nullptr, sEb, sSb,
      nullptr, nullptr, nullptr, nullptr, b1f, edw2, esw2, ted, tes);
  final_kernel<<<NB, 256, 0, stream>>>(sEb, sSb, feats, pair, pooled);
}

// Round 4
// 389.430 us; speedup vs baseline: 1.2249x; 1.0470x over previous
//
#include <hip/hip_runtime.h>
#include <cstdint>

typedef __bf16 bf16;
typedef __attribute__((ext_vector_type(8))) __bf16 bf16x8;
typedef __attribute__((ext_vector_type(4))) float f32x4;

#define CEPS 1e-5f
#define MROWS 65536   // B*T
#define NB 2048       // B
#define CDIM 512
#define K3C 1536

// fast gelu: tanh form via native exp; |err| <= ~3e-3 absolute
__device__ __forceinline__ float gelu_f(float x) {
  float x2 = x * x;
  float u = x * (0.7978845608f + 0.0356774081f * x2);   // sqrt(2/pi)*(x+0.044715x^3)
  float e = __expf(2.0f * u);
  float th = 1.0f - __fdividef(2.0f, e + 1.0f);          // tanh(u)
  return 0.5f * x * (1.0f + th);
}

__device__ __forceinline__ void gload_lds16(const void* g, void* l) {
  using GP = const __attribute__((address_space(1))) void*;
  using LP = __attribute__((address_space(3))) void*;
  __builtin_amdgcn_global_load_lds(reinterpret_cast<GP>(reinterpret_cast<uintptr_t>(g)),
                                   reinterpret_cast<LP>(reinterpret_cast<uintptr_t>(l)),
                                   16, 0, 0);
}

// ---------------- fold kernel
__global__ __launch_bounds__(256) void fold_kernel(
    const float* __restrict__ wmix, const float* __restrict__ bnm_g, const float* __restrict__ bnm_v,
    const float* __restrict__ edg, const float* __restrict__ edb,
    const float* __restrict__ esg, const float* __restrict__ esb,
    const float* __restrict__ w1a, const float* __restrict__ w1b,
    const float* __restrict__ b1a, const float* __restrict__ b1b,
    bf16* __restrict__ wmixf, bf16* __restrict__ w1f, float* __restrict__ b1f) {
  __shared__ float red[4];
  int bid = blockIdx.x, tid = threadIdx.x;
  if (bid < 512) {
    int o = bid;
    float s = bnm_g[o] * rsqrtf(bnm_v[o] + CEPS);
    for (int c = tid; c < K3C; c += 256)
      wmixf[(size_t)o * K3C + c] = (bf16)(wmix[(size_t)o * K3C + c] * s);
  } else {
    int n = bid - 512;
    int half = (n < 256) ? 0 : 1;
    const float* g  = half ? esg : edg;
    const float* lb = half ? esb : edb;
    const float* w1 = half ? w1b : w1a;
    const float* b1 = half ? b1b : b1a;
    int nn = n & 255;
    float dot = 0.f;
    for (int c = tid; c < 512; c += 256) {
      float w = w1[(size_t)nn * 512 + c];
      w1f[(size_t)n * 512 + c] = (bf16)(w * g[c]);
      dot += w * lb[c];
    }
    #pragma unroll
    for (int off = 1; off < 64; off <<= 1) dot += __shfl_xor(dot, off, 64);
    if ((tid & 63) == 0) red[tid >> 6] = dot;
    __syncthreads();
    if (tid == 0) b1f[n] = b1[nn] + red[0] + red[1] + red[2] + red[3];
  }
}

// ---------------- prep: x[b,c,64] -> tf, c3, c5 -> Acat[(b*32+t), {c, 512+c, 1024+c}] bf16
__global__ __launch_bounds__(512) void prep_kernel(
    const float* __restrict__ x,
    const float* __restrict__ w3, const float* __restrict__ bn3g, const float* __restrict__ bn3b,
    const float* __restrict__ bn3m, const float* __restrict__ bn3v,
    const float* __restrict__ w5, const float* __restrict__ bn5g, const float* __restrict__ bn5b,
    const float* __restrict__ bn5m, const float* __restrict__ bn5v,
    bf16* __restrict__ Acat) {
  int b = blockIdx.x, c = threadIdx.x;
  const float4* xp = (const float4*)(x + ((size_t)b * 512 + c) * 64);
  float tf[32];
  #pragma unroll
  for (int i = 0; i < 16; i++) {
    float4 v = xp[i];
    tf[2 * i]     = 0.5f * (v.x + v.y);
    tf[2 * i + 1] = 0.5f * (v.z + v.w);
  }
  float s3 = bn3g[c] * rsqrtf(bn3v[c] + CEPS), t3 = bn3b[c] - bn3m[c] * s3;
  float s5 = bn5g[c] * rsqrtf(bn5v[c] + CEPS), t5 = bn5b[c] - bn5m[c] * s5;
  float w30 = w3[c * 3], w31 = w3[c * 3 + 1], w32 = w3[c * 3 + 2];
  float w50 = w5[c * 5], w51 = w5[c * 5 + 1], w52 = w5[c * 5 + 2], w53 = w5[c * 5 + 3], w54 = w5[c * 5 + 4];
  bf16* Ab = Acat + (size_t)b * 32 * K3C + c;
  #pragma unroll
  for (int t = 0; t < 32; t++) {
    float tm2 = (t >= 2) ? tf[t - 2] : 0.f;
    float tm1 = (t >= 1) ? tf[t - 1] : 0.f;
    float tp1 = (t < 31) ? tf[t + 1] : 0.f;
    float tp2 = (t < 30) ? tf[t + 2] : 0.f;
    float c3 = gelu_f((w30 * tm1 + w31 * tf[t] + w32 * tp1) * s3 + t3);
    float c5 = gelu_f((w50 * tm2 + w51 * tm1 + w52 * tf[t] + w53 * tp1 + w54 * tp2) * s5 + t5);
    Ab[t * K3C]        = (bf16)tf[t];
    Ab[t * K3C + 512]  = (bf16)c3;
    Ab[t * K3C + 1024] = (bf16)c5;
  }
}

// ---------------- 8-phase 256x256 GEMM, precomputed-address edition
#define GBM 256
#define GBN 256
#define GBK 64

__device__ __forceinline__ int xcd_swz(int bid, int nwg) {
  int q = nwg >> 3, r = nwg & 7;
  int xcd = bid & 7, i = bid >> 3;
  return (xcd < r ? xcd * (q + 1) : r * (q + 1) + (xcd - r) * q) + i;
}

#define MFMA_Q(q)                                                     \
  __builtin_amdgcn_s_setprio(1);                                      \
  _Pragma("unroll")                                                   \
  for (int k2 = 0; k2 < 2; k2++)                                      \
    _Pragma("unroll")                                                 \
    for (int im = 0; im < 2; im++)                                    \
      _Pragma("unroll")                                               \
      for (int nr = 0; nr < 4; nr++)                                  \
        acc[2 * (q) + im][nr] = __builtin_amdgcn_mfma_f32_16x16x32_bf16( \
            Af[im][k2], Bf[nr][k2], acc[2 * (q) + im][nr], 0, 0, 0);  \
  __builtin_amdgcn_s_setprio(0);

#define LOAD_A(q)                                                     \
  bf16x8 Af[2][2];                                                    \
  _Pragma("unroll")                                                   \
  for (int im = 0; im < 2; im++) {                                    \
    Af[im][0] = *(const bf16x8*)(LA0 + (2 * (q) + im) * 2048);        \
    Af[im][1] = *(const bf16x8*)(LA1 + (2 * (q) + im) * 2048);        \
  }

template <int EPI, int KC>
__global__ __launch_bounds__(512, 2) void gemm8(
    const bf16* __restrict__ A, const bf16* __restrict__ Bm, bf16* __restrict__ out,
    float* __restrict__ sE, float* __restrict__ sS,
    const float* __restrict__ bn_g, const float* __restrict__ bn_b,
    const float* __restrict__ bn_m, const float* __restrict__ bn_v,
    const float* __restrict__ b1f,
    const float* __restrict__ w2a, const float* __restrict__ w2b,
    const float* __restrict__ ta, const float* __restrict__ tb) {
  __shared__ char lds[131072];   // 2 slots x (A 32KB + B 32KB)
  constexpr int KB = KC * 2;     // A/B row bytes
  constexpr int kt = KC / GBK;
  int tid = threadIdx.x;
  int wv = tid >> 6, lane = tid & 63;
  int wm = wv >> 2, wn = wv & 3;       // 2 x 4 wave grid
  int fr = lane & 15, kq = lane >> 4;
  int wgid = xcd_swz(blockIdx.x, gridDim.x);
  int mb = wgid >> 1, nb = wgid & 1;   // nblk = 512/256 = 2

  const bf16* Ag = A + (size_t)mb * GBM * KC;
  const bf16* Bg = Bm + (size_t)nb * GBN * KC;

  // ---- per-thread precomputed staging source pointers (swizzle baked in)
  int r0 = tid >> 3;
  int sc0 = ((tid & 7) << 4) ^ ((r0 & 7) << 4);
  const char* sAp = (const char*)Ag + (size_t)r0 * KB + sc0;
  const char* sBp = (const char*)Bg + (size_t)r0 * KB + sc0;
  const int wv1024 = wv * 1024;

  // ---- per-thread precomputed LDS read bases (swizzle algebraically separated)
  int ek0 = (kq << 4) ^ ((fr & 7) << 4);
  int ek1 = (64 | (kq << 4)) ^ ((fr & 7) << 4);
  int aB = wm * 16384 + fr * 128;
  int bB = 32768 + (wn >> 1) * 16384 + (((wn & 1) * 64 + fr) * 128);
  const int a0 = aB + ek0, a1 = aB + ek1;
  const int b0 = bB + ek0, b1 = bB + ek1;

  const f32x4 fz = {0.f, 0.f, 0.f, 0.f};
  f32x4 acc[8][4];
  #pragma unroll
  for (int i = 0; i < 8; i++)
    #pragma unroll
    for (int j = 0; j < 4; j++) acc[i][j] = fz;

  // ---- prologue: A(0),B(0) -> slot0; B(1) -> slot1
  {
    char* d = lds + wv1024;
    gload_lds16(sAp,               d);
    gload_lds16(sAp + 64 * KB,     d + 8192);
    gload_lds16(sAp + 128 * KB,    d + 16384);
    gload_lds16(sAp + 192 * KB,    d + 24576);
    gload_lds16(sBp,               d + 32768);
    gload_lds16(sBp + 64 * KB,     d + 40960);
    gload_lds16(sBp + 128 * KB,    d + 49152);
    gload_lds16(sBp + 192 * KB,    d + 57344);
    gload_lds16(sBp + 128,            d + 65536 + 32768);
    gload_lds16(sBp + 128 + 64 * KB,  d + 65536 + 40960);
    gload_lds16(sBp + 128 + 128 * KB, d + 65536 + 49152);
    gload_lds16(sBp + 128 + 192 * KB, d + 65536 + 57344);
  }
  asm volatile("s_waitcnt vmcnt(4)" ::: "memory");
  __builtin_amdgcn_s_barrier();

  for (int t = 0; t < kt; t++) {
    const int sofs = (t & 1) << 16;
    const char* LA0 = lds + sofs + a0;
    const char* LA1 = lds + sofs + a1;
    const char* LB0 = lds + sofs + b0;
    const char* LB1 = lds + sofs + b1;
    char* dA = lds + (sofs ^ 65536) + wv1024;
    char* dB = lds + sofs + wv1024;
    const bool stA = (t + 1 < kt), stB = (t + 2 < kt);
    bf16x8 Bf[4][2];

    // ---- phase 0: stage A-half0(t+1); read all B + A-quad0
    if (stA) { gload_lds16(sAp + 128, dA); gload_lds16(sAp + 128 + 64 * KB, dA + 8192); }
    #pragma unroll
    for (int nr = 0; nr < 4; nr++) {
      Bf[nr][0] = *(const bf16x8*)(LB0 + nr * 2048);
      Bf[nr][1] = *(const bf16x8*)(LB1 + nr * 2048);
    }
    {
      LOAD_A(0);
      __builtin_amdgcn_s_barrier();
      MFMA_Q(0);
    }
    __builtin_amdgcn_s_barrier();
    // ---- phase 1: stage A-half1(t+1); A-quad1
    if (stA) { gload_lds16(sAp + 128 + 128 * KB, dA + 16384); gload_lds16(sAp + 128 + 192 * KB, dA + 24576); }
    {
      LOAD_A(1);
      __builtin_amdgcn_s_barrier();
      MFMA_Q(1);
    }
    __builtin_amdgcn_s_barrier();
    // ---- phase 2: stage B-half0(t+2); A-quad2
    if (stB) { gload_lds16(sBp + 256, dB + 32768); gload_lds16(sBp + 256 + 64 * KB, dB + 40960); }
    {
      LOAD_A(2);
      __builtin_amdgcn_s_barrier();
      MFMA_Q(2);
    }
    __builtin_amdgcn_s_barrier();
    // ---- phase 3: stage B-half1(t+2); A-quad3; counted vmcnt once per K-tile
    if (stB) { gload_lds16(sBp + 256 + 128 * KB, dB + 49152); gload_lds16(sBp + 256 + 192 * KB, dB + 57344); }
    {
      LOAD_A(3);
      __builtin_amdgcn_s_barrier();
      MFMA_Q(3);
    }
    if (t < kt - 2) {
      asm volatile("s_waitcnt vmcnt(4)" ::: "memory");   // next tile's A+B complete
    } else if (t == kt - 2) {
      asm volatile("s_waitcnt vmcnt(0)" ::: "memory");   // drain
    }
    __builtin_amdgcn_s_barrier();
    sAp += 128;
    sBp += 128;
  }

  if constexpr (EPI == 0) {
    // gelu+bias, then coalesce C-store through XOR-swizzled LDS [256][256] bf16 tile
    int colb = (wn * 64 + fr) * 2;
    #pragma unroll
    for (int nr = 0; nr < 4; nr++) {
      int n = nb * GBN + wn * 64 + nr * 16 + fr;
      float sc = bn_g[n] * rsqrtf(bn_v[n] + CEPS);
      float bias = bn_b[n] - bn_m[n] * sc;
      #pragma unroll
      for (int mr = 0; mr < 8; mr++) {
        #pragma unroll
        for (int j = 0; j < 4; j++) {
          int row = wm * 128 + mr * 16 + kq * 4 + j;
          int ad = ((row << 9) + colb + nr * 32) ^ ((row & 15) << 5);
          *(bf16*)(lds + ad) = (bf16)gelu_f(acc[mr][nr][j] + bias);
        }
      }
    }
    __syncthreads();
    {
      int rr = tid >> 5;        // 16 rows per pass
      int ch = tid & 31;        // 16B chunk within 512B row
      size_t gbase = (size_t)(mb * GBM + rr) * CDIM + nb * GBN + ch * 8;
      #pragma unroll
      for (int p = 0; p < 16; p++) {
        int row = p * 16 + rr;
        int ad = ((row << 9) + ch * 16) ^ ((row & 15) << 5);
        bf16x8 v = *(const bf16x8*)(lds + ad);
        *(bf16x8*)(out + gbase + (size_t)p * 16 * CDIM) = v;
      }
    }
  } else {
    // fused row-reduction: s[m] = sum_n gelu(acc + b1f[n]) * w2s[n]
    float bias[4], w2s[4];
    #pragma unroll
    for (int nr = 0; nr < 4; nr++) {
      int n = nb * GBN + wn * 64 + nr * 16 + fr;
      bias[nr] = b1f[n];
      float tv = (n < 256) ? ta[0] : tb[0];
      tv = fminf(fmaxf(tv, 0.25f), 4.0f);
      w2s[nr] = ((n < 256) ? w2a[n] : w2b[n - 256]) / tv;
    }
    float* sred = (float*)lds;   // [4 wn][256 rows]
    __syncthreads();
    #pragma unroll
    for (int mr = 0; mr < 8; mr++) {
      float p0 = 0.f, p1 = 0.f, p2 = 0.f, p3 = 0.f;
      #pragma unroll
      for (int nr = 0; nr < 4; nr++) {
        p0 += gelu_f(acc[mr][nr][0] + bias[nr]) * w2s[nr];
        p1 += gelu_f(acc[mr][nr][1] + bias[nr]) * w2s[nr];
        p2 += gelu_f(acc[mr][nr][2] + bias[nr]) * w2s[nr];
        p3 += gelu_f(acc[mr][nr][3] + bias[nr]) * w2s[nr];
      }
      #pragma unroll
      for (int off = 1; off < 16; off <<= 1) {
        p0 += __shfl_xor(p0, off, 64);
        p1 += __shfl_xor(p1, off, 64);
        p2 += __shfl_xor(p2, off, 64);
        p3 += __shfl_xor(p3, off, 64);
      }
      if (fr == 0) {
        int rbase = wm * 128 + mr * 16 + kq * 4;
        sred[wn * 256 + rbase]     = p0;
        sred[wn * 256 + rbase + 1] = p1;
        sred[wn * 256 + rbase + 2] = p2;
        sred[wn * 256 + rbase + 3] = p3;
      }
    }
    __syncthreads();
    if (tid < 256) {
      float sv = sred[tid] + sred[256 + tid] + sred[512 + tid] + sred[768 + tid];
      float* so = nb ? sS : sE;
      so[(size_t)mb * GBM + tid] = sv;
    }
  }
}

// ---------------- LN: z = tf + ctx + pos; feats = LN(z)*g+b (f32); zhat = standardize(feats) bf16
__global__ __launch_bounds__(256) void ln_kernel(
    const bf16* __restrict__ Acat, const bf16* __restrict__ ctx, const float* __restrict__ pos,
    const float* __restrict__ lng, const float* __restrict__ lnb,
    float* __restrict__ feats, bf16* __restrict__ zhat) {
  int m = blockIdx.x * 4 + (threadIdx.x >> 6);
  int lane = threadIdx.x & 63;
  int c0 = lane * 8;
  int t = m & 31;
  bf16x8 tf8 = *(const bf16x8*)(Acat + (size_t)m * K3C + c0);
  bf16x8 cx8 = *(const bf16x8*)(ctx + (size_t)m * 512 + c0);
  const float* pp = pos + t * 512 + c0;
  float z[8], s = 0.f, ss = 0.f;
  #pragma unroll
  for (int j = 0; j < 8; j++) {
    z[j] = (float)tf8[j] + (float)cx8[j] + pp[j];
    s += z[j]; ss += z[j] * z[j];
  }
  #pragma unroll
  for (int off = 1; off < 64; off <<= 1) { s += __shfl_xor(s, off, 64); ss += __shfl_xor(ss, off, 64); }
  float mu = s * (1.f / 512.f);
  float var = ss * (1.f / 512.f) - mu * mu;
  float inv = rsqrtf(var + CEPS);
  float f[8], s2 = 0.f, ss2 = 0.f;
  #pragma unroll
  for (int j = 0; j < 8; j++) {
    f[j] = (z[j] - mu) * inv * lng[c0 + j] + lnb[c0 + j];
    s2 += f[j]; ss2 += f[j] * f[j];
  }
  float4* fo = (float4*)(feats + (size_t)m * 512 + c0);
  fo[0] = make_float4(f[0], f[1], f[2], f[3]);
  fo[1] = make_float4(f[4], f[5], f[6], f[7]);
  #pragma unroll
  for (int off = 1; off < 64; off <<= 1) { s2 += __shfl_xor(s2, off, 64); ss2 += __shfl_xor(ss2, off, 64); }
  float mu2 = s2 * (1.f / 512.f);
  float var2 = ss2 * (1.f / 512.f) - mu2 * mu2;
  float inv2 = rsqrtf(var2 + CEPS);
  bf16x8 zv;
  #pragma unroll
  for (int j = 0; j < 8; j++) zv[j] = (bf16)((f[j] - mu2) * inv2);
  *(bf16x8*)(zhat + (size_t)m * 512 + c0) = zv;
}

// ---------------- finalize: softmax over T per path from sE/sS; pair, pooled
__global__ __launch_bounds__(256) void final_kernel(
    const float* __restrict__ sE, const float* __restrict__ sS,
    const float* __restrict__ feats, float* __restrict__ pair, float* __restrict__ pooled) {
  __shared__ float wmL[32];
  int b = blockIdx.x, tid = threadIdx.x;
  if (tid < 32) {
    float vE = sE[(size_t)b * 32 + tid], vS = sS[(size_t)b * 32 + tid];
    float mE = vE, mS = vS;
    #pragma unroll
    for (int off = 1; off < 32; off <<= 1) {
      mE = fmaxf(mE, __shfl_xor(mE, off, 32));
      mS = fmaxf(mS, __shfl_xor(mS, off, 32));
    }
    float eE = expf(vE - mE), eS = expf(vS - mS);
    float sumE = eE, sumS = eS;
    #pragma unroll
    for (int off = 1; off < 32; off <<= 1) {
      sumE += __shfl_xor(sumE, off, 32);
      sumS += __shfl_xor(sumS, off, 32);
    }
    float awE = eE / sumE, awS = eS / sumS;
    size_t pidx = ((size_t)b * 32 + tid) * 2;
    pair[pidx] = awE;
    pair[pidx + 1] = awS;
    wmL[tid] = 0.5f * (awE + awS);
  }
  __syncthreads();
  {
    int c = tid * 2;
    float a0 = 0.f, a1 = 0.f;
    #pragma unroll
    for (int t = 0; t < 32; t++) {
      float2 v = *(const float2*)&feats[((size_t)b * 32 + t) * 512 + c];
      float w = wmL[t];
      a0 += v.x * w; a1 += v.y * w;
    }
    *(float2*)&pooled[(size_t)b * 512 + c] = make_float2(a0, a1);
  }
}

extern "C" void kernel_launch(void* const* d_in, const int* in_sizes, int n_in,
                              void* d_out, int out_size, void* d_ws, size_t ws_size,
                              hipStream_t stream) {
  const float* x     = (const float*)d_in[0];
  const float* pos   = (const float*)d_in[1];
  const float* w3    = (const float*)d_in[2];
  const float* bn3g  = (const float*)d_in[3];
  const float* bn3b  = (const float*)d_in[4];
  const float* bn3m  = (const float*)d_in[5];
  const float* bn3v  = (const float*)d_in[6];
  const float* w5    = (const float*)d_in[7];
  const float* bn5g  = (const float*)d_in[8];
  const float* bn5b  = (const float*)d_in[9];
  const float* bn5m  = (const float*)d_in[10];
  const float* bn5v  = (const float*)d_in[11];
  const float* wmix  = (const float*)d_in[12];
  const float* bnmg  = (const float*)d_in[13];
  const float* bnmb  = (const float*)d_in[14];
  const float* bnmm  = (const float*)d_in[15];
  const float* bnmv  = (const float*)d_in[16];
  const float* lng   = (const float*)d_in[17];
  const float* lnb   = (const float*)d_in[18];
  const float* edlng = (const float*)d_in[19];
  const float* edlnb = (const float*)d_in[20];
  const float* edw1  = (const float*)d_in[21];
  const float* edb1  = (const float*)d_in[22];
  const float* edw2  = (const float*)d_in[23];
  const float* eslng = (const float*)d_in[25];
  const float* eslnb = (const float*)d_in[26];
  const float* esw1  = (const float*)d_in[27];
  const float* esb1  = (const float*)d_in[28];
  const float* esw2  = (const float*)d_in[29];
  const float* ted   = (const float*)d_in[31];
  const float* tes   = (const float*)d_in[32];

  char* ws = (char*)d_ws;
  bf16* Acat  = (bf16*)ws;                        // 201,326,592 B
  bf16* ctx   = (bf16*)(ws + 201326592);          //  67,108,864 B
  bf16* zhat  = (bf16*)(ws + 268435456);          //  67,108,864 B
  bf16* wmixf = (bf16*)(ws + 335544320);          //   1,572,864 B
  bf16* w1f   = (bf16*)(ws + 337117184);          //     524,288 B
  float* b1f  = (float*)(ws + 337641472);         //       2,048 B
  float* sEb  = (float*)ws;                       // alias Acat (dead after ln_kernel)
  float* sSb  = (float*)(ws + 262144);

  float* feats  = (float*)d_out;
  float* pooled = feats + 33554432;   // B*T*C
  float* pair   = pooled + 1048576;   // + B*C

  fold_kernel<<<1024, 256, 0, stream>>>(wmix, bnmg, bnmv, edlng, edlnb, eslng, eslnb,
                                        edw1, esw1, edb1, esb1, wmixf, w1f, b1f);
  prep_kernel<<<NB, 512, 0, stream>>>(x, w3, bn3g, bn3b, bn3m, bn3v,
                                      w5, bn5g, bn5b, bn5m, bn5v, Acat);
  gemm8<0, K3C><<<(MROWS / GBM) * (CDIM / GBN), 512, 0, stream>>>(
      Acat, wmixf, ctx, nullptr, nullptr,
      bnmg, bnmb, bnmm, bnmv, nullptr, nullptr, nullptr, nullptr, nullptr);
  ln_kernel<<<MROWS / 4, 256, 0, stream>>>(Acat, ctx, pos, lng, lnb, feats, zhat);
  gemm8<1, CDIM><<<(MROWS / GBM) * (CDIM / GBN), 512, 0, stream>>>(
      zhat, w1f, nullptr, sEb, sSb,
      nullptr, nullptr, nullptr, nullptr, b1f, edw2, esw2, ted, tes);
  final_kernel<<<NB, 256, 0, stream>>>(sEb, sSb, feats, pair, pooled);
}

// Round 6
// 380.026 us; speedup vs baseline: 1.2552x; 1.0247x over previous
//
#include <hip/hip_runtime.h>
#include <cstdint>

typedef __bf16 bf16;
typedef __attribute__((ext_vector_type(8))) __bf16 bf16x8;
typedef __attribute__((ext_vector_type(4))) float f32x4;

#define CEPS 1e-5f
#define MROWS 65536   // B*T
#define NB 2048       // B
#define CDIM 512
#define K3C 1536
#define MKT 24        // K3C / 64

// fast gelu: tanh form via native exp; |err| <= ~3e-3 absolute
__device__ __forceinline__ float gelu_f(float x) {
  float x2 = x * x;
  float u = x * (0.7978845608f + 0.0356774081f * x2);
  float e = __expf(2.0f * u);
  float th = 1.0f - __fdividef(2.0f, e + 1.0f);
  return 0.5f * x * (1.0f + th);
}

__device__ __forceinline__ void gload_lds16(const void* g, void* l) {
  using GP = const __attribute__((address_space(1))) void*;
  using LP = __attribute__((address_space(3))) void*;
  __builtin_amdgcn_global_load_lds(reinterpret_cast<GP>(reinterpret_cast<uintptr_t>(g)),
                                   reinterpret_cast<LP>(reinterpret_cast<uintptr_t>(l)),
                                   16, 0, 0);
}

__device__ __forceinline__ int xcd_swz(int bid, int nwg) {
  int q = nwg >> 3, r = nwg & 7;
  int xcd = bid & 7, i = bid >> 3;
  return (xcd < r ? xcd * (q + 1) : r * (q + 1) + (xcd - r) * q) + i;
}

// ---------------- fold kernel
__global__ __launch_bounds__(256) void fold_kernel(
    const float* __restrict__ wmix, const float* __restrict__ bnm_g, const float* __restrict__ bnm_v,
    const float* __restrict__ edg, const float* __restrict__ edb,
    const float* __restrict__ esg, const float* __restrict__ esb,
    const float* __restrict__ w1a, const float* __restrict__ w1b,
    const float* __restrict__ b1a, const float* __restrict__ b1b,
    bf16* __restrict__ wmixf, bf16* __restrict__ w1f, float* __restrict__ b1f) {
  __shared__ float red[4];
  int bid = blockIdx.x, tid = threadIdx.x;
  if (bid < 512) {
    int o = bid;
    float s = bnm_g[o] * rsqrtf(bnm_v[o] + CEPS);
    for (int c = tid; c < K3C; c += 256)
      wmixf[(size_t)o * K3C + c] = (bf16)(wmix[(size_t)o * K3C + c] * s);
  } else {
    int n = bid - 512;
    int half = (n < 256) ? 0 : 1;
    const float* g  = half ? esg : edg;
    const float* lb = half ? esb : edb;
    const float* w1 = half ? w1b : w1a;
    const float* b1 = half ? b1b : b1a;
    int nn = n & 255;
    float dot = 0.f;
    for (int c = tid; c < 512; c += 256) {
      float w = w1[(size_t)nn * 512 + c];
      w1f[(size_t)n * 512 + c] = (bf16)(w * g[c]);
      dot += w * lb[c];
    }
    #pragma unroll
    for (int off = 1; off < 64; off <<= 1) dot += __shfl_xor(dot, off, 64);
    if ((tid & 63) == 0) red[tid >> 6] = dot;
    __syncthreads();
    if (tid == 0) b1f[n] = b1[nn] + red[0] + red[1] + red[2] + red[3];
  }
}

// ---------------- prep: x[b,c,64] -> tf, c3, c5 -> Acat[(b*32+t), {c, 512+c, 1024+c}] bf16
__global__ __launch_bounds__(512) void prep_kernel(
    const float* __restrict__ x,
    const float* __restrict__ w3, const float* __restrict__ bn3g, const float* __restrict__ bn3b,
    const float* __restrict__ bn3m, const float* __restrict__ bn3v,
    const float* __restrict__ w5, const float* __restrict__ bn5g, const float* __restrict__ bn5b,
    const float* __restrict__ bn5m, const float* __restrict__ bn5v,
    bf16* __restrict__ Acat) {
  int b = blockIdx.x, c = threadIdx.x;
  const float4* xp = (const float4*)(x + ((size_t)b * 512 + c) * 64);
  float tf[32];
  #pragma unroll
  for (int i = 0; i < 16; i++) {
    float4 v = xp[i];
    tf[2 * i]     = 0.5f * (v.x + v.y);
    tf[2 * i + 1] = 0.5f * (v.z + v.w);
  }
  float s3 = bn3g[c] * rsqrtf(bn3v[c] + CEPS), t3 = bn3b[c] - bn3m[c] * s3;
  float s5 = bn5g[c] * rsqrtf(bn5v[c] + CEPS), t5 = bn5b[c] - bn5m[c] * s5;
  float w30 = w3[c * 3], w31 = w3[c * 3 + 1], w32 = w3[c * 3 + 2];
  float w50 = w5[c * 5], w51 = w5[c * 5 + 1], w52 = w5[c * 5 + 2], w53 = w5[c * 5 + 3], w54 = w5[c * 5 + 4];
  bf16* Ab = Acat + (size_t)b * 32 * K3C + c;
  #pragma unroll
  for (int t = 0; t < 32; t++) {
    float tm2 = (t >= 2) ? tf[t - 2] : 0.f;
    float tm1 = (t >= 1) ? tf[t - 1] : 0.f;
    float tp1 = (t < 31) ? tf[t + 1] : 0.f;
    float tp2 = (t < 30) ? tf[t + 2] : 0.f;
    float c3 = gelu_f((w30 * tm1 + w31 * tf[t] + w32 * tp1) * s3 + t3);
    float c5 = gelu_f((w50 * tm2 + w51 * tm1 + w52 * tf[t] + w53 * tp1 + w54 * tp2) * s5 + t5);
    Ab[t * K3C]        = (bf16)tf[t];
    Ab[t * K3C + 512]  = (bf16)c3;
    Ab[t * K3C + 1024] = (bf16)c5;
  }
}

// ---------------- mega kernel: 128x512 mix GEMM + BN/gelu + LN + feats + zhat + attn MLPs + row-sums
// waves 2(wm) x 4(wn); wave tile 64 rows x 128 cols; acc[4 mr][8 nr]
#define MFMA1 __builtin_amdgcn_mfma_f32_16x16x32_bf16

#define PHASE(q)                                                              \
  {                                                                           \
    bf16x8 Bf[2][2];                                                          \
    _Pragma("unroll")                                                         \
    for (int i = 0; i < 2; i++) {                                             \
      Bf[i][0] = *(const bf16x8*)(lds + sl + bOff0 + (q) * 16384 + i * 2048); \
      Bf[i][1] = *(const bf16x8*)(lds + sl + bOff1 + (q) * 16384 + i * 2048); \
    }                                                                         \
    __builtin_amdgcn_s_barrier();                                             \
    __builtin_amdgcn_s_setprio(1);                                            \
    _Pragma("unroll")                                                         \
    for (int k2 = 0; k2 < 2; k2++)                                            \
      _Pragma("unroll")                                                       \
      for (int i = 0; i < 2; i++)                                             \
        _Pragma("unroll")                                                     \
        for (int mr = 0; mr < 4; mr++)                                        \
          acc[mr][2 * (q) + i] = MFMA1(Af[mr][k2], Bf[i][k2], acc[mr][2 * (q) + i], 0, 0, 0); \
    __builtin_amdgcn_s_setprio(0);                                            \
    if (stB) stageBq(sl, (q), t + 2);                                         \
  }

__global__ __launch_bounds__(512, 1) void mega_kernel(
    const bf16* __restrict__ Acat, const bf16* __restrict__ Bw, const bf16* __restrict__ w1f,
    const float* __restrict__ bn_g, const float* __restrict__ bn_b,
    const float* __restrict__ bn_m, const float* __restrict__ bn_v,
    const float* __restrict__ pos, const float* __restrict__ lng, const float* __restrict__ lnb,
    const float* __restrict__ b1f, const float* __restrict__ w2a, const float* __restrict__ w2b,
    const float* __restrict__ ta, const float* __restrict__ tb,
    float* __restrict__ feats, float* __restrict__ sE, float* __restrict__ sS) {
  __shared__ char lds[163840];  // 2 slots x (A 16KB + B 64KB); epilogue reuses
  int tid = threadIdx.x;
  int wv = tid >> 6, lane = tid & 63;
  int wm = wv >> 2, wn = wv & 3;
  int fr = lane & 15, kq = lane >> 4;
  int mb = xcd_swz(blockIdx.x, gridDim.x);   // 512 m-blocks

  const size_t AKB = 3072;  // Acat / wmixf row bytes
  const char* Ablk = (const char*)Acat + (size_t)mb * 128 * AKB;

  // staging precompute (global src pre-swizzled; LDS dest linear — rule #21)
  int r8 = tid >> 3;                                   // 0..63
  int colx = ((tid & 7) << 4) ^ ((r8 & 7) << 4);
  const char* pA = Ablk + (size_t)r8 * AKB + colx;
  int r32 = r8 & 31, st0 = r8 >> 5;
  const char* pB = (const char*)Bw + (size_t)(st0 * 128 + r32) * AKB
                 + (((tid & 7) << 4) ^ ((r32 & 7) << 4));
  const int dstIdx = tid * 16;

  // LDS read bases: k2=0 and k2=1 variants (64-byte K-offset participates in the XOR!)
  int e0 = (kq << 4) ^ ((fr & 7) << 4);
  int e1 = (64 | (kq << 4)) ^ ((fr & 7) << 4);
  int aB_ = (wm * 64 + fr) * 128;
  int bB_ = 16384 + (wn * 32 + fr) * 128;
  const int aOff0 = aB_ + e0, aOff1 = aB_ + e1;
  const int bOff0 = bB_ + e0, bOff1 = bB_ + e1;

  auto stageA = [&](int slot, int t) {
    char* d = lds + slot + dstIdx;
    const char* s = pA + (size_t)t * 128;
    gload_lds16(s, d);
    gload_lds16(s + 64 * AKB, d + 8192);
  };
  auto stageBq = [&](int slot, int q, int t) {
    char* d = lds + slot + 16384 + q * 16384 + dstIdx;
    const char* s = pB + (size_t)q * 32 * AKB + (size_t)t * 128;
    gload_lds16(s, d);
    gload_lds16(s + 256 * AKB, d + 8192);
  };

  const f32x4 fz = {0.f, 0.f, 0.f, 0.f};
  f32x4 acc[4][8];
  #pragma unroll
  for (int i = 0; i < 4; i++)
    #pragma unroll
    for (int j = 0; j < 8; j++) acc[i][j] = fz;

  // prologue: A(0),B(0) -> slot0; B(1) -> slot1
  stageA(0, 0);
  #pragma unroll
  for (int q = 0; q < 4; q++) stageBq(0, q, 0);
  #pragma unroll
  for (int q = 0; q < 4; q++) stageBq(81920, q, 1);
  asm volatile("s_waitcnt vmcnt(8)" ::: "memory");
  __builtin_amdgcn_s_barrier();

  for (int t = 0; t < MKT; t++) {
    const int sl = (t & 1) * 81920;
    const bool stA = (t + 1 < MKT), stB = (t + 2 < MKT);
    if (stA) stageA(sl ^ 81920, t + 1);
    bf16x8 Af[4][2];
    #pragma unroll
    for (int mr = 0; mr < 4; mr++) {
      Af[mr][0] = *(const bf16x8*)(lds + sl + aOff0 + mr * 2048);
      Af[mr][1] = *(const bf16x8*)(lds + sl + aOff1 + mr * 2048);
    }
    PHASE(0);
    __builtin_amdgcn_s_barrier();
    PHASE(1);
    __builtin_amdgcn_s_barrier();
    PHASE(2);
    __builtin_amdgcn_s_barrier();
    PHASE(3);
    if (t < MKT - 2) {
      asm volatile("s_waitcnt vmcnt(8)" ::: "memory");
    } else if (t == MKT - 2) {
      asm volatile("s_waitcnt vmcnt(0)" ::: "memory");
    }
    __builtin_amdgcn_s_barrier();
  }

  // ---- E1: ctx = gelu(acc + bn_bias) in-register
  {
    float biasm[8];
    #pragma unroll
    for (int nr = 0; nr < 8; nr++) {
      int n = wn * 128 + nr * 16 + fr;
      float s = bn_g[n] * rsqrtf(bn_v[n] + CEPS);
      biasm[nr] = bn_b[n] - bn_m[n] * s;
    }
    #pragma unroll
    for (int mr = 0; mr < 4; mr++)
      #pragma unroll
      for (int nr = 0; nr < 8; nr++)
        #pragma unroll
        for (int j = 0; j < 4; j++)
          acc[mr][nr][j] = gelu_f(acc[mr][nr][j] + biasm[nr]);
  }
  __syncthreads();
  // ---- E2: stage tf tile [128 rows][1024B] swizzled into lds[0..131072)
  {
    const char* ptf = Ablk + (size_t)wv * AKB + ((lane * 16) ^ (wv << 4));
    char* d = lds + wv * 1024 + lane * 16;
    #pragma unroll
    for (int l = 0; l < 16; l++) gload_lds16(ptf + (size_t)l * 8 * AKB, d + l * 8192);
  }
  __syncthreads();
  float* sst  = (float*)(lds + 131072);   // [128][4] float2
  float* minv = (float*)(lds + 135168);   // [128] float2
  // ---- E3: z = ctx + tf + pos; stats1
  {
    float s1[4][4], s2[4][4];
    #pragma unroll
    for (int mr = 0; mr < 4; mr++)
      #pragma unroll
      for (int j = 0; j < 4; j++) { s1[mr][j] = 0.f; s2[mr][j] = 0.f; }
    #pragma unroll
    for (int mr = 0; mr < 4; mr++)
      #pragma unroll
      for (int j = 0; j < 4; j++) {
        int r = wm * 64 + mr * 16 + kq * 4 + j;
        int swz = (r & 7) << 4;
        #pragma unroll
        for (int nr = 0; nr < 8; nr++) {
          int c = wn * 128 + nr * 16 + fr;
          float tfv = (float)*(const bf16*)(lds + r * 1024 + ((c * 2) ^ swz));
          float z = acc[mr][nr][j] + tfv + pos[(r & 31) * 512 + c];
          acc[mr][nr][j] = z;
          s1[mr][j] += z; s2[mr][j] += z * z;
        }
      }
    #pragma unroll
    for (int mr = 0; mr < 4; mr++)
      #pragma unroll
      for (int j = 0; j < 4; j++)
        #pragma unroll
        for (int off = 1; off < 16; off <<= 1) {
          s1[mr][j] += __shfl_xor(s1[mr][j], off, 64);
          s2[mr][j] += __shfl_xor(s2[mr][j], off, 64);
        }
    if (fr == 0) {
      #pragma unroll
      for (int mr = 0; mr < 4; mr++)
        #pragma unroll
        for (int j = 0; j < 4; j++) {
          int r = wm * 64 + mr * 16 + kq * 4 + j;
          ((float2*)sst)[r * 4 + wn] = make_float2(s1[mr][j], s2[mr][j]);
        }
    }
  }
  __syncthreads();
  if (tid < 128) {
    float a = 0.f, b = 0.f;
    #pragma unroll
    for (int w = 0; w < 4; w++) { float2 v = ((float2*)sst)[tid * 4 + w]; a += v.x; b += v.y; }
    float mu = a * (1.f / 512.f);
    float var = b * (1.f / 512.f) - mu * mu;
    ((float2*)minv)[tid] = make_float2(mu, rsqrtf(var + CEPS));
  }
  __syncthreads();
  // ---- E5: feats = (z-mu)*inv*g + b; stats2
  {
    float g_[8], b_[8];
    #pragma unroll
    for (int nr = 0; nr < 8; nr++) {
      int c = wn * 128 + nr * 16 + fr;
      g_[nr] = lng[c]; b_[nr] = lnb[c];
    }
    float t1[4][4], t2[4][4];
    #pragma unroll
    for (int mr = 0; mr < 4; mr++)
      #pragma unroll
      for (int j = 0; j < 4; j++) { t1[mr][j] = 0.f; t2[mr][j] = 0.f; }
    #pragma unroll
    for (int mr = 0; mr < 4; mr++)
      #pragma unroll
      for (int j = 0; j < 4; j++) {
        int r = wm * 64 + mr * 16 + kq * 4 + j;
        float2 mi = ((float2*)minv)[r];
        #pragma unroll
        for (int nr = 0; nr < 8; nr++) {
          int c = wn * 128 + nr * 16 + fr;
          float f = (acc[mr][nr][j] - mi.x) * mi.y * g_[nr] + b_[nr];
          acc[mr][nr][j] = f;
          feats[((size_t)mb * 128 + r) * 512 + c] = f;
          t1[mr][j] += f; t2[mr][j] += f * f;
        }
      }
    #pragma unroll
    for (int mr = 0; mr < 4; mr++)
      #pragma unroll
      for (int j = 0; j < 4; j++)
        #pragma unroll
        for (int off = 1; off < 16; off <<= 1) {
          t1[mr][j] += __shfl_xor(t1[mr][j], off, 64);
          t2[mr][j] += __shfl_xor(t2[mr][j], off, 64);
        }
    if (fr == 0) {
      #pragma unroll
      for (int mr = 0; mr < 4; mr++)
        #pragma unroll
        for (int j = 0; j < 4; j++) {
          int r = wm * 64 + mr * 16 + kq * 4 + j;
          ((float2*)sst)[r * 4 + wn] = make_float2(t1[mr][j], t2[mr][j]);
        }
    }
  }
  __syncthreads();
  if (tid < 128) {
    float a = 0.f, b = 0.f;
    #pragma unroll
    for (int w = 0; w < 4; w++) { float2 v = ((float2*)sst)[tid * 4 + w]; a += v.x; b += v.y; }
    float mu = a * (1.f / 512.f);
    float var = b * (1.f / 512.f) - mu * mu;
    ((float2*)minv)[tid] = make_float2(mu, rsqrtf(var + CEPS));
  }
  __syncthreads();
  // ---- E6: zhat -> LDS [0..131072), swizzled (same convention the attn reads expect)
  #pragma unroll
  for (int mr = 0; mr < 4; mr++)
    #pragma unroll
    for (int j = 0; j < 4; j++) {
      int r = wm * 64 + mr * 16 + kq * 4 + j;
      int swz = (r & 7) << 4;
      float2 mi = ((float2*)minv)[r];
      #pragma unroll
      for (int nr = 0; nr < 8; nr++) {
        int c = wn * 128 + nr * 16 + fr;
        *(bf16*)(lds + r * 1024 + ((c * 2) ^ swz)) = (bf16)((acc[mr][nr][j] - mi.x) * mi.y);
      }
    }
  __syncthreads();
  // ---- E7: attn passes; acc reused as h-accumulator [4 mr][h*4+nr]
  #pragma unroll
  for (int i = 0; i < 4; i++)
    #pragma unroll
    for (int j = 0; j < 8; j++) acc[i][j] = fz;
  float b1l[8], w2l[8];
  #pragma unroll
  for (int h = 0; h < 2; h++) {
    float tv = fminf(fmaxf(h ? tb[0] : ta[0], 0.25f), 4.0f);
    #pragma unroll
    for (int nr = 0; nr < 4; nr++) {
      int np = wn * 64 + nr * 16 + fr;
      b1l[h * 4 + nr] = b1f[h * 256 + np];
      w2l[h * 4 + nr] = (h ? w2b[np] : w2a[np]) / tv;
    }
  }
  {
    const char* pW = (const char*)w1f + (size_t)r8 * 1024 + colx;
    int azB = (wm * 64 + fr) * 1024;
    int abB = 131072 + (wn * 64 + fr) * 128;
    const int azOff0 = azB + e0, azOff1 = azB + e1;
    const int abOff0 = abB + e0, abOff1 = abB + e1;
    #pragma unroll
    for (int h = 0; h < 2; h++) {
      {
        char* d = lds + 131072 + dstIdx;
        #pragma unroll
        for (int l = 0; l < 4; l++)
          gload_lds16(pW + h * 262144 + l * 65536, d + l * 8192);
      }
      __syncthreads();
      for (int kk = 0; kk < 8; kk++) {
        bf16x8 pf[4];
        if (kk < 7) {
          #pragma unroll
          for (int l = 0; l < 4; l++)
            pf[l] = *(const bf16x8*)(pW + h * 262144 + l * 65536 + (kk + 1) * 128);
        }
        bf16x8 Az[4][2], Bz[4][2];
        #pragma unroll
        for (int mr = 0; mr < 4; mr++) {
          Az[mr][0] = *(const bf16x8*)(lds + azOff0 + mr * 16384 + kk * 128);
          Az[mr][1] = *(const bf16x8*)(lds + azOff1 + mr * 16384 + kk * 128);
        }
        #pragma unroll
        for (int nr = 0; nr < 4; nr++) {
          Bz[nr][0] = *(const bf16x8*)(lds + abOff0 + nr * 2048);
          Bz[nr][1] = *(const bf16x8*)(lds + abOff1 + nr * 2048);
        }
        __builtin_amdgcn_s_setprio(1);
        #pragma unroll
        for (int k2 = 0; k2 < 2; k2++)
          #pragma unroll
          for (int mr = 0; mr < 4; mr++)
            #pragma unroll
            for (int nr = 0; nr < 4; nr++)
              acc[mr][h * 4 + nr] = MFMA1(Az[mr][k2], Bz[nr][k2], acc[mr][h * 4 + nr], 0, 0, 0);
        __builtin_amdgcn_s_setprio(0);
        if (kk < 7) {
          __syncthreads();
          char* d = lds + 131072 + dstIdx;
          #pragma unroll
          for (int l = 0; l < 4; l++) *(bf16x8*)(d + l * 8192) = pf[l];
          __syncthreads();
        }
      }
      __syncthreads();
    }
  }
  // ---- E8: s[m] = sum_n gelu(h + b1f)*w2s, per path
  {
    float pE[4][4], pS[4][4];
    #pragma unroll
    for (int mr = 0; mr < 4; mr++)
      #pragma unroll
      for (int j = 0; j < 4; j++) { pE[mr][j] = 0.f; pS[mr][j] = 0.f; }
    #pragma unroll
    for (int mr = 0; mr < 4; mr++)
      #pragma unroll
      for (int j = 0; j < 4; j++)
        #pragma unroll
        for (int q8 = 0; q8 < 8; q8++) {
          float hh = gelu_f(acc[mr][q8][j] + b1l[q8]) * w2l[q8];
          if (q8 < 4) pE[mr][j] += hh; else pS[mr][j] += hh;
        }
    #pragma unroll
    for (int mr = 0; mr < 4; mr++)
      #pragma unroll
      for (int j = 0; j < 4; j++)
        #pragma unroll
        for (int off = 1; off < 16; off <<= 1) {
          pE[mr][j] += __shfl_xor(pE[mr][j], off, 64);
          pS[mr][j] += __shfl_xor(pS[mr][j], off, 64);
        }
    float* sstE = (float*)(lds + 131072);  // [128][4]
    float* sstS = (float*)(lds + 133120);
    if (fr == 0) {
      #pragma unroll
      for (int mr = 0; mr < 4; mr++)
        #pragma unroll
        for (int j = 0; j < 4; j++) {
          int r = wm * 64 + mr * 16 + kq * 4 + j;
          sstE[r * 4 + wn] = pE[mr][j];
          sstS[r * 4 + wn] = pS[mr][j];
        }
    }
    __syncthreads();
    if (tid < 128) {
      float aE = sstE[tid * 4] + sstE[tid * 4 + 1] + sstE[tid * 4 + 2] + sstE[tid * 4 + 3];
      float aS = sstS[tid * 4] + sstS[tid * 4 + 1] + sstS[tid * 4 + 2] + sstS[tid * 4 + 3];
      sE[(size_t)mb * 128 + tid] = aE;
      sS[(size_t)mb * 128 + tid] = aS;
    }
  }
}

// ---------------- finalize: softmax over T per path from sE/sS; pair, pooled
__global__ __launch_bounds__(256) void final_kernel(
    const float* __restrict__ sE, const float* __restrict__ sS,
    const float* __restrict__ feats, float* __restrict__ pair, float* __restrict__ pooled) {
  __shared__ float wmL[32];
  int b = blockIdx.x, tid = threadIdx.x;
  if (tid < 32) {
    float vE = sE[(size_t)b * 32 + tid], vS = sS[(size_t)b * 32 + tid];
    float mE = vE, mS = vS;
    #pragma unroll
    for (int off = 1; off < 32; off <<= 1) {
      mE = fmaxf(mE, __shfl_xor(mE, off, 32));
      mS = fmaxf(mS, __shfl_xor(mS, off, 32));
    }
    float eE = expf(vE - mE), eS = expf(vS - mS);
    float sumE = eE, sumS = eS;
    #pragma unroll
    for (int off = 1; off < 32; off <<= 1) {
      sumE += __shfl_xor(sumE, off, 32);
      sumS += __shfl_xor(sumS, off, 32);
    }
    float awE = eE / sumE, awS = eS / sumS;
    size_t pidx = ((size_t)b * 32 + tid) * 2;
    pair[pidx] = awE;
    pair[pidx + 1] = awS;
    wmL[tid] = 0.5f * (awE + awS);
  }
  __syncthreads();
  {
    int c = tid * 2;
    float a0 = 0.f, a1 = 0.f;
    #pragma unroll
    for (int t = 0; t < 32; t++) {
      float2 v = *(const float2*)&feats[((size_t)b * 32 + t) * 512 + c];
      float w = wmL[t];
      a0 += v.x * w; a1 += v.y * w;
    }
    *(float2*)&pooled[(size_t)b * 512 + c] = make_float2(a0, a1);
  }
}

extern "C" void kernel_launch(void* const* d_in, const int* in_sizes, int n_in,
                              void* d_out, int out_size, void* d_ws, size_t ws_size,
                              hipStream_t stream) {
  const float* x     = (const float*)d_in[0];
  const float* pos   = (const float*)d_in[1];
  const float* w3    = (const float*)d_in[2];
  const float* bn3g  = (const float*)d_in[3];
  const float* bn3b  = (const float*)d_in[4];
  const float* bn3m  = (const float*)d_in[5];
  const float* bn3v  = (const float*)d_in[6];
  const float* w5    = (const float*)d_in[7];
  const float* bn5g  = (const float*)d_in[8];
  const float* bn5b  = (const float*)d_in[9];
  const float* bn5m  = (const float*)d_in[10];
  const float* bn5v  = (const float*)d_in[11];
  const float* wmix  = (const float*)d_in[12];
  const float* bnmg  = (const float*)d_in[13];
  const float* bnmb  = (const float*)d_in[14];
  const float* bnmm  = (const float*)d_in[15];
  const float* bnmv  = (const float*)d_in[16];
  const float* lng   = (const float*)d_in[17];
  const float* lnb   = (const float*)d_in[18];
  const float* edlng = (const float*)d_in[19];
  const float* edlnb = (const float*)d_in[20];
  const float* edw1  = (const float*)d_in[21];
  const float* edb1  = (const float*)d_in[22];
  const float* edw2  = (const float*)d_in[23];
  const float* eslng = (const float*)d_in[25];
  const float* eslnb = (const float*)d_in[26];
  const float* esw1  = (const float*)d_in[27];
  const float* esb1  = (const float*)d_in[28];
  const float* esw2  = (const float*)d_in[29];
  const float* ted   = (const float*)d_in[31];
  const float* tes   = (const float*)d_in[32];

  char* ws = (char*)d_ws;
  bf16* Acat  = (bf16*)ws;                        // 201,326,592 B
  bf16* wmixf = (bf16*)(ws + 201326592);          //   1,572,864 B
  bf16* w1f   = (bf16*)(ws + 202899456);          //     524,288 B
  float* b1f  = (float*)(ws + 203423744);         //       2,048 B
  float* sEb  = (float*)(ws + 203425792);         //     262,144 B
  float* sSb  = (float*)(ws + 203687936);         //     262,144 B

  float* feats  = (float*)d_out;
  float* pooled = feats + 33554432;   // B*T*C
  float* pair   = pooled + 1048576;   // + B*C

  fold_kernel<<<1024, 256, 0, stream>>>(wmix, bnmg, bnmv, edlng, edlnb, eslng, eslnb,
                                        edw1, esw1, edb1, esb1, wmixf, w1f, b1f);
  prep_kernel<<<NB, 512, 0, stream>>>(x, w3, bn3g, bn3b, bn3m, bn3v,
                                      w5, bn5g, bn5b, bn5m, bn5v, Acat);
  mega_kernel<<<MROWS / 128, 512, 0, stream>>>(
      Acat, wmixf, w1f, bnmg, bnmb, bnmm, bnmv, pos, lng, lnb,
      b1f, edw2, esw2, ted, tes, feats, sEb, sSb);
  final_kernel<<<NB, 256, 0, stream>>>(sEb, sSb, feats, pair, pooled);
}